// Round 11
// baseline (444.794 us; speedup 1.0000x reference)
//
#include <hip/hip_runtime.h>

// ---------------------------------------------------------------------------
// EncoderLayer: S=1024, B=4, D=1024, H=16, dh=64, DFF=4096. fp32 I/O.
// R20: revert to R16 champion (424.8us: split qk_strip + pv_smx, BK=64 GL16
// STAGE=1 GEMMs, fused QKV SPLIT3) -- the attn fusion line (R18/R19) lost to
// the split at equal math (149 vs ~121-126us) because 1 blk/CU fusion can't
// hide its VALU+LDS chain; 268MB HBM saved < parallelism lost. One change vs
// R16: pv_smx grid 256 -> 512 (16h x 32 s-strips of 32 rows), waves =
// (row-group x nj-half), acc[4][2]: 2 blocks/CU = 8 waves/CU (was 1 blk/CU,
// 4 waves -> latency-exposed). Softmax duplicated across nj-half waves.
//
// Workspace map (224 MB):
//  [0,16M)    O f32  (first 8MB doubles as relwT bf16 until pv)
//  [16M,24M) Yq bf16  [24M,32M) Yk  [32M,40M) Yv   (contiguous for SPLIT3)
//  [40M,48M)  h1 bf16  [48M,80M) ffn1 bf16
//  [80M,96M)  ffn2 f32 (first 8MB doubles as YvT bf16 until ffn2 GEMM)
//  [96M,224M) scores bf16 (RAW; consumed by pv_smx)
//    overlap (pre-qk):  xb@96M(8MB) wqb@104M wkb@106M wvb@108M (contiguous B)
//    overlap (post-pv): w1b@96M(8MB) w2b@104M(8MB)
// ---------------------------------------------------------------------------

typedef unsigned short u16;
typedef unsigned int u32;
typedef __attribute__((ext_vector_type(4))) float f32x4;
typedef __attribute__((ext_vector_type(8))) short bf16x8;
typedef __attribute__((ext_vector_type(4))) u32 u32x4;

__device__ __forceinline__ float bf2f(u16 u) { return __uint_as_float(((u32)u) << 16); }
__device__ __forceinline__ u16 f2bf(float f) {
    u32 u = __float_as_uint(f);
    u += 0x7fffu + ((u >> 16) & 1u);   // RNE
    return (u16)(u >> 16);
}
template<int DT>
__device__ __forceinline__ float load1(const void* P, size_t idx) {
    return (DT == 0) ? bf2f(((const u16*)P)[idx]) : ((const float*)P)[idx];
}

// async global->LDS DMA, 16B per lane. LDS dest linear in lane order
// (wave-uniform base + lane*16); swizzle lives on the GLOBAL address.
#define GL16(gp, lp)                                                        \
    __builtin_amdgcn_global_load_lds(                                       \
        (const __attribute__((address_space(1))) void*)(gp),                \
        (__attribute__((address_space(3))) void*)(lp), 16, 0, 0)

__global__ __launch_bounds__(256) void sentinel_ws(float* out, u32 n)
{
    for (u32 i = blockIdx.x * 256 + threadIdx.x; i < n; i += gridDim.x * 256) out[i] = 31000.0f;
}

// ---------------- fp32 -> bf16 bulk convert (n mult of 4) ------------------
__global__ __launch_bounds__(256) void cvt_f32_bf16(const float* __restrict__ s,
                                                    u16* __restrict__ d, u32 n)
{
    u32 i = (blockIdx.x * 256 + threadIdx.x) * 4;
    if (i >= n) return;
    float4 v = *(const float4*)(s + i);
    uint2 pk;
    pk.x = (u32)f2bf(v.x) | ((u32)f2bf(v.y) << 16);
    pk.y = (u32)f2bf(v.z) | ((u32)f2bf(v.w) << 16);
    *(uint2*)(d + i) = pk;
}

// ------- relwT[bh][u][d] (bf16) = relw[bh][d][u] (fp32) --------------------
__global__ __launch_bounds__(256) void relw_tr(const float* __restrict__ relw,
                                               u16* __restrict__ relwT)
{
    __shared__ __align__(16) float T[64][68];
    const int tid = threadIdx.x;
    const int bh = blockIdx.y;
    const int u0 = blockIdx.x << 6;
    {
        const int d = tid >> 2, uq = (tid & 3) << 4;
        const float* rp = relw + (size_t)bh * 65536 + (size_t)d * 1024 + u0 + uq;
#pragma unroll
        for (int i = 0; i < 4; i++)
            *(float4*)&T[d][uq + i * 4] = *(const float4*)(rp + i * 4);
    }
    __syncthreads();
    {
        const int u = tid >> 2, dq = (tid & 3) << 4;
        u32 pk[8];
#pragma unroll
        for (int p = 0; p < 8; p++) {
            float a = T[dq + p * 2][u], b = T[dq + p * 2 + 1][u];
            pk[p] = (u32)f2bf(a) | ((u32)f2bf(b) << 16);
        }
        u16* op = relwT + ((size_t)(bh * 1024 + u0 + u) << 6) + dq;
        *(uint4*)op = *(uint4*)&pk[0];
        *(uint4*)(op + 8) = *(uint4*)&pk[4];
    }
}

// ------- YvT[bh][d][t] (bf16) = Yv[(b*1024+t)*1024 + h*64+d] ---------------
__global__ __launch_bounds__(256) void yv_tr(const u16* __restrict__ Yv,
                                             u16* __restrict__ YvT)
{
    __shared__ __align__(16) u16 T[64][72];
    const int tid = threadIdx.x;
    const int bh = blockIdx.y, b = bh >> 4, h = bh & 15;
    const int t0 = blockIdx.x << 6;
    {
        const int r = tid >> 2, cq = (tid & 3) << 4;
        const u16* p = Yv + ((size_t)(b * 1024 + t0 + r) << 10) + h * 64 + cq;
        *(uint4*)&T[r][cq] = *(const uint4*)p;
        *(uint4*)&T[r][cq + 8] = *(const uint4*)(p + 8);
    }
    __syncthreads();
    {
        const int d = tid >> 2, tq = (tid & 3) << 4;
        u16 vals[16];
#pragma unroll
        for (int p = 0; p < 16; p++) vals[p] = T[tq + p][d];
        u16* op = YvT + (((size_t)bh * 64 + d) << 10) + t0 + tq;
        *(uint4*)op = ((uint4*)vals)[0];
        *(uint4*)(op + 8) = ((uint4*)vals)[1];
    }
}

// --------------- MFMA GEMM: C[M,N] = act(A[M,K] @ B[N,K]^T + bias) ---------
// 128x128 tile, 4 waves, 4x4 mfma_f32_16x16x32_bf16 per wave.
// STAGE=1: BK=64, GL16 single-buffer (barrier/DMA/barrier/32 MFMA). Row-XOR
//   slot swizzle on the global source; ds_read at slot^(row&7); 2-way free.
// STAGE=0: BK=32 register-prefetch staging (1-block/CU grids).
// SPLIT3: C column c -> segment c>>10 (Yq/Yk/Yv contiguous, 4M elems apart).
template<int RELU, int OUT_F32, int HAS_BIAS, int SPLIT3, int STAGE>
__global__ __launch_bounds__(256) void mfma_gemm(
    const u16* __restrict__ A, const u16* __restrict__ B,
    const float* __restrict__ bias, void* __restrict__ Cout,
    int M, int N, int K)
{
    __shared__ __align__(16) u16 As[8192];   // STAGE=1: [128][64]; STAGE=0: uses 4096
    __shared__ __align__(16) u16 Bs[8192];
    const int tid = threadIdx.x;
    const int wave = tid >> 6, lane = tid & 63;
    const int quad = lane >> 4, l16 = lane & 15;
    const int m0 = blockIdx.y << 7, n0 = blockIdx.x << 7;
    const int wm = (wave >> 1) << 6, wn = (wave & 1) << 6;

    f32x4 acc[4][4];
#pragma unroll
    for (int i = 0; i < 4; i++)
#pragma unroll
        for (int j = 0; j < 4; j++) acc[i][j] = (f32x4){0.f, 0.f, 0.f, 0.f};

    if (STAGE) {
        // ---- BK=64 GL16 path ----
        const int srow = tid >> 3;                                // 0..31
        const int csw = ((tid & 7) ^ ((tid >> 3) & 7)) << 3;      // src slot-XOR
        const u16* Ags = A + (size_t)(m0 + srow) * K + csw;
        const u16* Bgs = B + (size_t)(n0 + srow) * K + csw;
        const int rx = (l16 & 7) << 3;                            // read slot-XOR (elems)

        for (int k0 = 0; k0 < K; k0 += 64) {
            __syncthreads();                   // prior reads of LDS done
#pragma unroll
            for (int i = 0; i < 4; i++) {
                GL16(Ags + (size_t)(i * 32) * K + k0, &As[(i * 256 + tid) * 8]);
                GL16(Bgs + (size_t)(i * 32) * K + k0, &Bs[(i * 256 + tid) * 8]);
            }
            __syncthreads();                   // vmcnt(0) drain: tile resident

#pragma unroll
            for (int kk = 0; kk < 2; kk++) {
                bf16x8 af[4], bfr[4];
#pragma unroll
                for (int mi = 0; mi < 4; mi++)
                    af[mi] = *(const bf16x8*)(As + ((wm + mi * 16 + l16) << 6) +
                                              ((((kk * 4 + quad) << 3) ^ rx)));
#pragma unroll
                for (int ni = 0; ni < 4; ni++)
                    bfr[ni] = *(const bf16x8*)(Bs + ((wn + ni * 16 + l16) << 6) +
                                               ((((kk * 4 + quad) << 3) ^ rx)));
#pragma unroll
                for (int mi = 0; mi < 4; mi++)
#pragma unroll
                    for (int ni = 0; ni < 4; ni++)
                        acc[mi][ni] = __builtin_amdgcn_mfma_f32_16x16x32_bf16(
                            af[mi], bfr[ni], acc[mi][ni], 0, 0, 0);
            }
        }
    } else {
        // ---- BK=32 register-prefetch path (R14-proven) ----
        const int r0 = tid >> 2;
        const int csw = ((tid & 3) ^ ((r0 >> 1) & 3)) << 3;
        const u16* Ag0 = A + (size_t)(m0 + r0) * K + csw;
        const u16* Ag1 = A + (size_t)(m0 + r0 + 64) * K + csw;
        const u16* Bg0 = B + (size_t)(n0 + r0) * K + csw;
        const u16* Bg1 = B + (size_t)(n0 + r0 + 64) * K + csw;
        const int pb = ((quad ^ ((l16 >> 1) & 3)) << 3);

        uint4 a0 = *(const uint4*)(Ag0);
        uint4 a1 = *(const uint4*)(Ag1);
        uint4 b0 = *(const uint4*)(Bg0);
        uint4 b1 = *(const uint4*)(Bg1);

        for (int k0 = 0; k0 < K; k0 += 32) {
            __syncthreads();
            *(uint4*)(As + tid * 8)        = a0;
            *(uint4*)(As + 2048 + tid * 8) = a1;
            *(uint4*)(Bs + tid * 8)        = b0;
            *(uint4*)(Bs + 2048 + tid * 8) = b1;
            __syncthreads();

            if (k0 + 32 < K) {                // prefetch next tile
                a0 = *(const uint4*)(Ag0 + k0 + 32);
                a1 = *(const uint4*)(Ag1 + k0 + 32);
                b0 = *(const uint4*)(Bg0 + k0 + 32);
                b1 = *(const uint4*)(Bg1 + k0 + 32);
            }

            bf16x8 af[4], bfr[4];
#pragma unroll
            for (int mi = 0; mi < 4; mi++)
                af[mi] = *(const bf16x8*)(As + ((wm + mi * 16 + l16) << 5) + pb);
#pragma unroll
            for (int ni = 0; ni < 4; ni++)
                bfr[ni] = *(const bf16x8*)(Bs + ((wn + ni * 16 + l16) << 5) + pb);
#pragma unroll
            for (int mi = 0; mi < 4; mi++)
#pragma unroll
                for (int ni = 0; ni < 4; ni++)
                    acc[mi][ni] = __builtin_amdgcn_mfma_f32_16x16x32_bf16(
                        af[mi], bfr[ni], acc[mi][ni], 0, 0, 0);
        }
    }

    float bb[4];
#pragma unroll
    for (int ni = 0; ni < 4; ni++)
        bb[ni] = HAS_BIAS ? bias[n0 + wn + ni * 16 + l16] : 0.f;

#pragma unroll
    for (int mi = 0; mi < 4; mi++) {
#pragma unroll
        for (int ni = 0; ni < 4; ni++) {
            const int col = n0 + wn + ni * 16 + l16;
            const size_t cb = SPLIT3
                ? (((size_t)(col >> 10) << 22) + (size_t)(col & 1023))
                : (size_t)col;
#pragma unroll
            for (int r = 0; r < 4; r++) {
                const int row = m0 + wm + mi * 16 + quad * 4 + r;
                float v = acc[mi][ni][r] + bb[ni];
                if (RELU) v = fmaxf(v, 0.f);
                const size_t idx = SPLIT3 ? (cb + ((size_t)row << 10))
                                          : ((size_t)row * N + cb);
                if (OUT_F32) ((float*)Cout)[idx] = v;
                else ((u16*)Cout)[idx] = f2bf(v);
            }
        }
    }
}

// ---------------- scores strip kernel: QK^T/8 + rel-pos skew ----------------
// grid (16 s-strips, 64 bh). Block owns rows [s0,s0+64) of scores[bh] and
// loops t0 over 16 tiles of 64. 4 waves in a 2x2 (s,t) split.
// LDS = 53760 B exactly: the PROVEN 3-blocks/CU size (54016+ drops to 2).
__global__ __launch_bounds__(256) void qk_strip(
    const u16* __restrict__ Yq, const u16* __restrict__ Yk,
    const u16* __restrict__ relwT, u16* __restrict__ scores)
{
    // LDS: Ks [64][72] | Rw 2x[64][72] | Eb [64][132] | Ssh [64][72]
    __shared__ __align__(16) u16 lds[26880];          // 53760 B -> 3 blocks/CU
    u16* Ks  = lds;
    u16* Rw  = lds + 4608;
    u16* Eb  = lds + 13824;
    u16* Ssh = lds + 22272;

    const int tid = threadIdx.x;
    const int wave = tid >> 6, lane = tid & 63;
    const int quad = lane >> 4, l16 = lane & 15;
    const int ws = wave >> 1, wt = wave & 1;

    // XCD-aware swizzle: 1024 blocks, 8 XCDs -> contiguous 128-block chunks
    const int linb = blockIdx.y * 16 + blockIdx.x;
    const int swz = (linb & 7) * 128 + (linb >> 3);
    const int si = swz & 15, bh = swz >> 4;
    const int b = bh >> 4, h = bh & 15;
    const int s0 = si << 6;
    const int qb0 = 15 - si;                   // U0(iter0) >> 6
    const int tau0 = 2 + wt * 2 - ws * 2;      // wave's first c-tile (of 16)

    // Q fragments (rows = wave's 32 s, k = dh=64 in two 32-chunks)
    bf16x8 qf[2][2];
#pragma unroll
    for (int mi = 0; mi < 2; mi++)
#pragma unroll
        for (int kk = 0; kk < 2; kk++)
            qf[mi][kk] = *(const bf16x8*)(Yq +
                ((size_t)(b * 1024 + s0 + ws * 32 + mi * 16 + l16) << 10) +
                h * 64 + kk * 32 + quad * 8);

    // staging thread map: row r (0..63), 16-col chunk cq
    const int r = tid >> 2, cq = (tid & 3) << 4;
    const u16* Kg = Yk + ((size_t)(b * 1024 + r) << 10) + h * 64 + cq;
    const u16* Rg = relwT + ((size_t)bh << 16) + cq;

    uint4 kp0, kp1, rp0, rp1, ri0, ri1;
    kp0 = *(const uint4*)(Kg);
    kp1 = *(const uint4*)(Kg + 8);
    {   // initial Rw half: u in [960-s0, 1024-s0)  (always valid rows)
        const u16* p = Rg + ((size_t)(960 - s0 + r) << 6);
        ri0 = *(const uint4*)p; ri1 = *(const uint4*)(p + 8);
    }
    {   // half staged at iter 0: u in [1024-s0, 1088-s0), zero-fill u>=1024
        const int u = 1024 - s0 + r;
        uint4 z = {0, 0, 0, 0};
        rp0 = z; rp1 = z;
        if (u < 1024) {
            const u16* p = Rg + ((size_t)u << 6);
            rp0 = *(const uint4*)p; rp1 = *(const uint4*)(p + 8);
        }
    }

    for (int i = 0; i < 16; i++) {
        const int t0 = i << 6;
        __syncthreads();                       // prev-iter LDS readers done
        *(uint4*)(Ks + r * 72 + cq)     = kp0;
        *(uint4*)(Ks + r * 72 + cq + 8) = kp1;
        if (i == 0) {
            u16* hb = Rw + (qb0 & 1) * 4608;
            *(uint4*)(hb + r * 72 + cq)     = ri0;
            *(uint4*)(hb + r * 72 + cq + 8) = ri1;
        }
        if (i <= si) {
            u16* hb = Rw + ((qb0 + i + 1) & 1) * 4608;
            *(uint4*)(hb + r * 72 + cq)     = rp0;
            *(uint4*)(hb + r * 72 + cq + 8) = rp1;
        }
        __syncthreads();                       // staged data visible

        // prefetch next tile into regs (overlaps with MFMA below)
        if (i + 1 < 16) {
            const u16* p = Kg + ((size_t)(i + 1) << 16);
            kp0 = *(const uint4*)p; kp1 = *(const uint4*)(p + 8);
        }
        if (i + 1 <= si) {
            const int u = 1024 - s0 + ((i + 1) << 6) + r;
            uint4 z = {0, 0, 0, 0};
            rp0 = z; rp1 = z;
            if (u < 1024) {
                const u16* p = Rg + ((size_t)u << 6);
                rp0 = *(const uint4*)p; rp1 = *(const uint4*)(p + 8);
            }
        }

        // ---- QK^T quadrant: 2mi x 2nj, K=64 ----
        f32x4 aqk[2][2];
#pragma unroll
        for (int mi = 0; mi < 2; mi++)
#pragma unroll
            for (int nj = 0; nj < 2; nj++) aqk[mi][nj] = (f32x4){0.f, 0.f, 0.f, 0.f};
#pragma unroll
        for (int kk = 0; kk < 2; kk++)
#pragma unroll
            for (int nj = 0; nj < 2; nj++) {
                bf16x8 kb = *(const bf16x8*)(Ks + (wt * 32 + nj * 16 + l16) * 72 +
                                             kk * 32 + quad * 8);
#pragma unroll
                for (int mi = 0; mi < 2; mi++)
                    aqk[mi][nj] = __builtin_amdgcn_mfma_f32_16x16x32_bf16(
                        qf[mi][kk], kb, aqk[mi][nj], 0, 0, 0);
            }

        const int eact = (i <= si);
        if (eact) {
            // ---- E^T tiles: rows=u (4 tiles from tau0), cols=s (2 mi) ----
            const int qb = qb0 + i;
            f32x4 ae[4][2];
#pragma unroll
            for (int uj = 0; uj < 4; uj++)
#pragma unroll
                for (int mi = 0; mi < 2; mi++) ae[uj][mi] = (f32x4){0.f, 0.f, 0.f, 0.f};
#pragma unroll
            for (int kk = 0; kk < 2; kk++)
#pragma unroll
                for (int uj = 0; uj < 4; uj++) {
                    const int tau = tau0 + uj;
                    const u16* hp = Rw + ((qb + (tau >> 2)) & 1) * 4608;
                    bf16x8 ra = *(const bf16x8*)(hp + ((tau & 3) * 16 + l16) * 72 +
                                                 kk * 32 + quad * 8);
#pragma unroll
                    for (int mi = 0; mi < 2; mi++)
                        ae[uj][mi] = __builtin_amdgcn_mfma_f32_16x16x32_bf16(
                            ra, qf[mi][kk], ae[uj][mi], 0, 0, 0);
                }
            // pack 4 consecutive-u values -> b64 into row-major Eb[s][c]
#pragma unroll
            for (int uj = 0; uj < 4; uj++)
#pragma unroll
                for (int mi = 0; mi < 2; mi++) {
                    const int scol = ws * 32 + mi * 16 + l16;
                    const int cb = (tau0 + uj) * 16 + quad * 4;
                    uint2 pk;
                    pk.x = (u32)f2bf(ae[uj][mi][0]) | ((u32)f2bf(ae[uj][mi][1]) << 16);
                    pk.y = (u32)f2bf(ae[uj][mi][2]) | ((u32)f2bf(ae[uj][mi][3]) << 16);
                    *(uint2*)(Eb + scol * 132 + cb) = pk;
                }
        }

        // ---- combine + stage to Ssh (wave-local quadrant) ----
#pragma unroll
        for (int mi = 0; mi < 2; mi++)
#pragma unroll
            for (int nj = 0; nj < 2; nj++)
#pragma unroll
                for (int rr = 0; rr < 4; rr++) {
                    const int sl = ws * 32 + mi * 16 + quad * 4 + rr;
                    const int tl = wt * 32 + nj * 16 + l16;
                    float e = 0.f;
                    if (eact) e = bf2f(Eb[sl * 131 + 63 + tl]);  // = [sl][63+tl-sl]
                    Ssh[sl * 72 + tl] = f2bf(aqk[mi][nj][rr] * 0.125f + e);
                }

        // ---- coalesced write of the wave's own 32x32 quadrant ----
        {
            const int row = ws * 32 + (lane >> 1);
            const int col = wt * 32 + ((lane & 1) << 4);
            uint4 v0 = *(const uint4*)(Ssh + row * 72 + col);
            uint4 v1 = *(const uint4*)(Ssh + row * 72 + col + 8);
            u16* op = scores + (((size_t)bh * 1024 + s0 + row) << 10) + t0 + col;
            *(uint4*)op = v0;
            *(uint4*)(op + 8) = v1;
        }
    }
}

// ------------- fused batch-softmax + PV -----------------------------------
// O[bh][s][d] = sum_t softmax_b(scraw)[bh][s][t] * YvT[bh][d][t]
// R20: grid 512 = (16 h) x (32 s-strips of 32 rows), 4 waves as
// (row-group wr x nj-half wn): 2 blocks/CU = 8 waves/CU (was 1 blk/CU).
// Softmax over batch done in-register on directly-loaded per-lane P
// fragments (duplicated across the two nj-half waves). All staging regs are
// u32x4 ext-vectors with constant-only indexing (no scratch).
__global__ __launch_bounds__(256) void pv_smx(
    const u16* __restrict__ scraw, const u16* __restrict__ YvT,
    float* __restrict__ O)
{
    __shared__ __align__(16) u16 Vt[18432];    // V[4][64 d][72] = 36 KB
    const int tid = threadIdx.x;
    const int w = tid >> 6, lane = tid & 63;
    const int quad = lane >> 4, l16 = lane & 15;
    const int wr = w >> 1, wn = w & 1;         // row-group, nj-half

    // h-major XCD swizzle: 512 blocks -> XCD k owns 64 consecutive (h,strip)
    const int bid = blockIdx.x;
    const int swz = (bid & 7) * 64 + (bid >> 3);
    const int h = swz >> 5, si2 = swz & 31;
    const int s0 = si2 << 5;                   // 32-row strip

    // per-lane direct P fragment base: row (s0 + wr*16 + l16), col quad*8
    const u16* Pl = scraw + ((size_t)(h * 1024 + s0 + wr * 16 + l16) << 10) + quad * 8;
    // V staging map (full d=64 x t=64 tile, independent of s-rows)
    const int sr0 = tid >> 3, sc0 = (tid & 7) << 3;
    const u16* Vg = YvT + ((size_t)h << 16) + ((size_t)sr0 << 10) + sc0;

    f32x4 acc[4][2];
#pragma unroll
    for (int b = 0; b < 4; b++)
#pragma unroll
        for (int j = 0; j < 2; j++) acc[b][j] = (f32x4){0.f, 0.f, 0.f, 0.f};

    u32x4 pc[4][2], pn[4][2], vc[4][2], vn[4][2];
#pragma unroll
    for (int b = 0; b < 4; b++) {
        pc[b][0] = *(const u32x4*)(Pl + ((size_t)b << 24));
        pc[b][1] = *(const u32x4*)(Pl + ((size_t)b << 24) + 32);
        vc[b][0] = *(const u32x4*)(Vg + ((size_t)b << 20));
        vc[b][1] = *(const u32x4*)(Vg + ((size_t)b << 20) + (32 << 10));
    }

    for (int t0 = 0; t0 < 1024; t0 += 64) {
        __syncthreads();
#pragma unroll
        for (int b = 0; b < 4; b++) {
            *(u32x4*)(Vt + b * 4608 + sr0 * 72 + sc0)        = vc[b][0];
            *(u32x4*)(Vt + b * 4608 + (sr0 + 32) * 72 + sc0) = vc[b][1];
        }
        __syncthreads();

        const int more = (t0 + 64 < 1024);
        if (more) {                            // prefetch next chunk (regs)
#pragma unroll
            for (int b = 0; b < 4; b++) {
                pn[b][0] = *(const u32x4*)(Pl + ((size_t)b << 24) + t0 + 64);
                pn[b][1] = *(const u32x4*)(Pl + ((size_t)b << 24) + t0 + 96);
                vn[b][0] = *(const u32x4*)(Vg + ((size_t)b << 20) + t0 + 64);
                vn[b][1] = *(const u32x4*)(Vg + ((size_t)b << 20) + (32 << 10) + t0 + 64);
            }
        }

#pragma unroll
        for (int kk = 0; kk < 2; kk++) {
            // in-register 4-way batch softmax on the raw fragment words
            u32x4 aw[4];
#pragma unroll
            for (int j = 0; j < 4; j++) {
                float x0[4], x1[4];
#pragma unroll
                for (int b = 0; b < 4; b++) {
                    const u32 wd = pc[b][kk][j];
                    x0[b] = __uint_as_float(wd << 16);
                    x1[b] = __uint_as_float(wd & 0xffff0000u);
                }
                const float m0 = fmaxf(fmaxf(x0[0], x0[1]), fmaxf(x0[2], x0[3]));
                const float m1 = fmaxf(fmaxf(x1[0], x1[1]), fmaxf(x1[2], x1[3]));
                float s0v = 0.f, s1v = 0.f;
#pragma unroll
                for (int b = 0; b < 4; b++) {
                    x0[b] = __expf(x0[b] - m0); s0v += x0[b];
                    x1[b] = __expf(x1[b] - m1); s1v += x1[b];
                }
                const float r0 = 1.f / s0v, r1 = 1.f / s1v;
#pragma unroll
                for (int b = 0; b < 4; b++)
                    aw[b][j] = (u32)f2bf(x0[b] * r0) | ((u32)f2bf(x1[b] * r1) << 16);
            }
#pragma unroll
            for (int b = 0; b < 4; b++) {
                const bf16x8 af = __builtin_bit_cast(bf16x8, aw[b]);
#pragma unroll
                for (int njl = 0; njl < 2; njl++) {
                    const int nj = wn * 2 + njl;
                    bf16x8 bv = *(const bf16x8*)(Vt + b * 4608 + (nj * 16 + l16) * 72 +
                                                 kk * 32 + quad * 8);
                    acc[b][njl] = __builtin_amdgcn_mfma_f32_16x16x32_bf16(
                        af, bv, acc[b][njl], 0, 0, 0);
                }
            }
        }

        if (more) {
#pragma unroll
            for (int b = 0; b < 4; b++) {
                pc[b][0] = pn[b][0]; pc[b][1] = pn[b][1];
                vc[b][0] = vn[b][0]; vc[b][1] = vn[b][1];
            }
        }
    }

#pragma unroll
    for (int b = 0; b < 4; b++)
#pragma unroll
        for (int njl = 0; njl < 2; njl++)
#pragma unroll
            for (int rr = 0; rr < 4; rr++) {
                const int row = s0 + wr * 16 + quad * 4 + rr;
                const int col = (wn * 2 + njl) * 16 + l16;
                O[((((size_t)(b * 16 + h) << 10) + row) << 6) + col] =
                    acc[b][njl][rr];
            }
}

// ------------- out = LN(A + f32 B) * g + beta ------------------------------
template<int DTA, int OUT_F32>
__global__ __launch_bounds__(256) void add_ln(
    const void* __restrict__ A, const float* __restrict__ Bf,
    const float* __restrict__ g, const float* __restrict__ beta,
    void* __restrict__ out)
{
    const int row = blockIdx.x;
    const int tid = threadIdx.x;
    const size_t base = (size_t)row * 1024;
    float v[4], s1 = 0.f, s2 = 0.f;
#pragma unroll
    for (int k = 0; k < 4; k++) {
        const int c = k * 256 + tid;
        float t = load1<DTA>(A, base + c) + Bf[base + c];
        v[k] = t; s1 += t; s2 += t * t;
    }
#pragma unroll
    for (int m = 1; m < 64; m <<= 1) {
        s1 += __shfl_xor(s1, m, 64);
        s2 += __shfl_xor(s2, m, 64);
    }
    __shared__ float red[8];
    if ((tid & 63) == 0) { red[(tid >> 6) * 2] = s1; red[(tid >> 6) * 2 + 1] = s2; }
    __syncthreads();
    s1 = red[0] + red[2] + red[4] + red[6];
    s2 = red[1] + red[3] + red[5] + red[7];
    const float mean = s1 * (1.f / 1024.f);
    const float var = s2 * (1.f / 1024.f) - mean * mean;
    const float rstd = rsqrtf(var + 1e-5f);
#pragma unroll
    for (int k = 0; k < 4; k++) {
        const int c = k * 256 + tid;
        float o = (v[k] - mean) * rstd * g[c] + beta[c];
        if (OUT_F32) ((float*)out)[base + c] = o;
        else ((u16*)out)[base + c] = f2bf(o);
    }
}

// ---------------------------------------------------------------------------
extern "C" void kernel_launch(void* const* d_in, const int* in_sizes, int n_in,
                              void* d_out, int out_size, void* d_ws, size_t ws_size,
                              hipStream_t stream)
{
    const float* x    = (const float*)d_in[0];
    const float* wq   = (const float*)d_in[1];
    const float* wk   = (const float*)d_in[2];
    const float* wv   = (const float*)d_in[3];
    const float* relw = (const float*)d_in[4];
    const float* g1   = (const float*)d_in[5];
    const float* be1  = (const float*)d_in[6];
    const float* g2   = (const float*)d_in[7];
    const float* be2  = (const float*)d_in[8];
    const float* w1   = (const float*)d_in[9];
    const float* b1   = (const float*)d_in[10];
    const float* w2   = (const float*)d_in[11];
    const float* b2   = (const float*)d_in[12];

    const size_t NEEDED = ((size_t)224 << 20);
    if (ws_size < NEEDED) {
        sentinel_ws<<<dim3(1024), dim3(256), 0, stream>>>((float*)d_out, (u32)out_size);
        return;
    }

    char* ws = (char*)d_ws;
    float* O     = (float*)(ws);
    u16*   relwT = (u16*)(ws);                                  // dies before pv
    u16*   Yq    = (u16*)(ws + ((size_t)16 << 20));             // Yq/Yk/Yv contig
    u16*   Yk    = (u16*)(ws + ((size_t)24 << 20));
    u16*   Yv    = (u16*)(ws + ((size_t)32 << 20));
    u16*   h1    = (u16*)(ws + ((size_t)40 << 20));
    u16*   ffn1  = (u16*)(ws + ((size_t)48 << 20));
    float* ffn2  = (float*)(ws + ((size_t)80 << 20));
    u16*   YvT   = (u16*)(ws + ((size_t)80 << 20));             // dies before ffn2
    u16*   sc    = (u16*)(ws + ((size_t)96 << 20));
    u16*   xb    = (u16*)(ws + ((size_t)96 << 20));             // pre-qk
    u16*   wqb   = (u16*)(ws + ((size_t)104 << 20));            // wq|wk|wv contig
    u16*   wkb   = (u16*)(ws + ((size_t)106 << 20));
    u16*   wvb   = (u16*)(ws + ((size_t)108 << 20));
    u16*   w1b   = (u16*)(ws + ((size_t)96 << 20));             // post-pv
    u16*   w2b   = (u16*)(ws + ((size_t)104 << 20));

    dim3 blk(256);
    const u32 M4 = 4u << 20, M1 = 1u << 20;

    // fp32 -> bf16 staging + relw transpose
    cvt_f32_bf16<<<dim3(M4 / 1024), blk, 0, stream>>>(x,  xb,  M4);
    cvt_f32_bf16<<<dim3(M1 / 1024), blk, 0, stream>>>(wq, wqb, M1);
    cvt_f32_bf16<<<dim3(M1 / 1024), blk, 0, stream>>>(wk, wkb, M1);
    cvt_f32_bf16<<<dim3(M1 / 1024), blk, 0, stream>>>(wv, wvb, M1);
    relw_tr<<<dim3(16, 64), blk, 0, stream>>>(relw, relwT);

    // fused QKV projection: B=[wq;wk;wv] (3072x1024), C split into Yq/Yk/Yv
    // 768 blocks = 3/CU -> BK=64 GL16 schedule (STAGE=1)
    mfma_gemm<0,0,0,1,1><<<dim3(24, 32), blk, 0, stream>>>(
        xb, wqb, nullptr, Yq, 4096, 3072, 1024);
    yv_tr<<<dim3(16, 64), blk, 0, stream>>>(Yv, YvT);

    // scores strip kernel (raw) + fused batch-softmax+PV (512 blocks)
    qk_strip<<<dim3(16, 64), blk, 0, stream>>>(Yq, Yk, relwT, sc);
    pv_smx<<<dim3(512), blk, 0, stream>>>(sc, YvT, O);

    // h1 = LN(x + attn_out)
    add_ln<1,0><<<dim3(4096), blk, 0, stream>>>(x, O, g1, be1, h1);

    // FFN weights -> bf16 (scores region dead after pv)
    cvt_f32_bf16<<<dim3(M4 / 1024), blk, 0, stream>>>(w1, w1b, M4);
    cvt_f32_bf16<<<dim3(M4 / 1024), blk, 0, stream>>>(w2, w2b, M4);

    // FFN (MFMA): ffn1 1024 blocks = 4/CU -> STAGE=1 BK=64; ffn2 256 = 1/CU -> STAGE=0
    mfma_gemm<1,0,1,0,1><<<dim3(32, 32), blk, 0, stream>>>(h1, w1b, b1, ffn1, 4096, 4096, 1024);
    mfma_gemm<0,1,1,0,0><<<dim3(8, 32), blk, 0, stream>>>(ffn1, w2b, b2, ffn2, 4096, 1024, 4096);

    // out = LN(h1 + ffn) -> f32
    add_ln<0,1><<<dim3(4096), blk, 0, stream>>>(h1, ffn2, g2, be2, (float*)d_out);
}

// Round 12
// 426.334 us; speedup vs baseline: 1.0433x; 1.0433x over previous
//
#include <hip/hip_runtime.h>

// ---------------------------------------------------------------------------
// EncoderLayer: S=1024, B=4, D=1024, H=16, dh=64, DFF=4096. fp32 I/O.
// R21: R16 champion base (424.8us) + pv_smx split over t-halves.
//  - R20's nj-half wave split DUPLICATED the softmax (VALU 70%, pv 84us).
//    Softmax is per-(s,t): splitting over t PARTITIONS it instead. grid
//    (256,2): blockIdx.y = t-half; each block = R16-exact pv_smx (softmax
//    once per fragment, acc[4][4]) over 8 t-chunks; partial O to O0/O1.
//    2 blocks/CU = 8 waves/CU, total VALU unchanged -> wall ~halved.
//  - add_ln<TWOB=1> folds O0+O1 into the h1 LayerNorm (memory-bound kernel,
//    +16MB read ~= +2.5us; no extra reduction kernel).
//  - O1 lives at ws+48M (ffn1 region, dead until ffn1 GEMM which launches
//    after add_ln completes -- same stream, safe).
// All other kernels byte-exact R16 champion.
//
// Workspace map (224 MB):
//  [0,16M)    O0 f32  (first 8MB doubles as relwT bf16 until pv)
//  [16M,24M) Yq bf16  [24M,32M) Yk  [32M,40M) Yv   (contiguous for SPLIT3)
//  [40M,48M)  h1 bf16  [48M,80M) ffn1 bf16 (first 16MB doubles as O1 f32
//             until add_ln consumes it)
//  [80M,96M)  ffn2 f32 (first 8MB doubles as YvT bf16 until ffn2 GEMM)
//  [96M,224M) scores bf16 (RAW; consumed by pv_smx)
//    overlap (pre-qk):  xb@96M(8MB) wqb@104M wkb@106M wvb@108M (contiguous B)
//    overlap (post-pv): w1b@96M(8MB) w2b@104M(8MB)
// ---------------------------------------------------------------------------

typedef unsigned short u16;
typedef unsigned int u32;
typedef __attribute__((ext_vector_type(4))) float f32x4;
typedef __attribute__((ext_vector_type(8))) short bf16x8;
typedef __attribute__((ext_vector_type(4))) u32 u32x4;

__device__ __forceinline__ float bf2f(u16 u) { return __uint_as_float(((u32)u) << 16); }
__device__ __forceinline__ u16 f2bf(float f) {
    u32 u = __float_as_uint(f);
    u += 0x7fffu + ((u >> 16) & 1u);   // RNE
    return (u16)(u >> 16);
}
template<int DT>
__device__ __forceinline__ float load1(const void* P, size_t idx) {
    return (DT == 0) ? bf2f(((const u16*)P)[idx]) : ((const float*)P)[idx];
}

// async global->LDS DMA, 16B per lane. LDS dest linear in lane order
// (wave-uniform base + lane*16); swizzle lives on the GLOBAL address.
#define GL16(gp, lp)                                                        \
    __builtin_amdgcn_global_load_lds(                                       \
        (const __attribute__((address_space(1))) void*)(gp),                \
        (__attribute__((address_space(3))) void*)(lp), 16, 0, 0)

__global__ __launch_bounds__(256) void sentinel_ws(float* out, u32 n)
{
    for (u32 i = blockIdx.x * 256 + threadIdx.x; i < n; i += gridDim.x * 256) out[i] = 31000.0f;
}

// ---------------- fp32 -> bf16 bulk convert (n mult of 4) ------------------
__global__ __launch_bounds__(256) void cvt_f32_bf16(const float* __restrict__ s,
                                                    u16* __restrict__ d, u32 n)
{
    u32 i = (blockIdx.x * 256 + threadIdx.x) * 4;
    if (i >= n) return;
    float4 v = *(const float4*)(s + i);
    uint2 pk;
    pk.x = (u32)f2bf(v.x) | ((u32)f2bf(v.y) << 16);
    pk.y = (u32)f2bf(v.z) | ((u32)f2bf(v.w) << 16);
    *(uint2*)(d + i) = pk;
}

// ------- relwT[bh][u][d] (bf16) = relw[bh][d][u] (fp32) --------------------
__global__ __launch_bounds__(256) void relw_tr(const float* __restrict__ relw,
                                               u16* __restrict__ relwT)
{
    __shared__ __align__(16) float T[64][68];
    const int tid = threadIdx.x;
    const int bh = blockIdx.y;
    const int u0 = blockIdx.x << 6;
    {
        const int d = tid >> 2, uq = (tid & 3) << 4;
        const float* rp = relw + (size_t)bh * 65536 + (size_t)d * 1024 + u0 + uq;
#pragma unroll
        for (int i = 0; i < 4; i++)
            *(float4*)&T[d][uq + i * 4] = *(const float4*)(rp + i * 4);
    }
    __syncthreads();
    {
        const int u = tid >> 2, dq = (tid & 3) << 4;
        u32 pk[8];
#pragma unroll
        for (int p = 0; p < 8; p++) {
            float a = T[dq + p * 2][u], b = T[dq + p * 2 + 1][u];
            pk[p] = (u32)f2bf(a) | ((u32)f2bf(b) << 16);
        }
        u16* op = relwT + ((size_t)(bh * 1024 + u0 + u) << 6) + dq;
        *(uint4*)op = *(uint4*)&pk[0];
        *(uint4*)(op + 8) = *(uint4*)&pk[4];
    }
}

// ------- YvT[bh][d][t] (bf16) = Yv[(b*1024+t)*1024 + h*64+d] ---------------
__global__ __launch_bounds__(256) void yv_tr(const u16* __restrict__ Yv,
                                             u16* __restrict__ YvT)
{
    __shared__ __align__(16) u16 T[64][72];
    const int tid = threadIdx.x;
    const int bh = blockIdx.y, b = bh >> 4, h = bh & 15;
    const int t0 = blockIdx.x << 6;
    {
        const int r = tid >> 2, cq = (tid & 3) << 4;
        const u16* p = Yv + ((size_t)(b * 1024 + t0 + r) << 10) + h * 64 + cq;
        *(uint4*)&T[r][cq] = *(const uint4*)p;
        *(uint4*)&T[r][cq + 8] = *(const uint4*)(p + 8);
    }
    __syncthreads();
    {
        const int d = tid >> 2, tq = (tid & 3) << 4;
        u16 vals[16];
#pragma unroll
        for (int p = 0; p < 16; p++) vals[p] = T[tq + p][d];
        u16* op = YvT + (((size_t)bh * 64 + d) << 10) + t0 + tq;
        *(uint4*)op = ((uint4*)vals)[0];
        *(uint4*)(op + 8) = ((uint4*)vals)[1];
    }
}

// --------------- MFMA GEMM: C[M,N] = act(A[M,K] @ B[N,K]^T + bias) ---------
// 128x128 tile, 4 waves, 4x4 mfma_f32_16x16x32_bf16 per wave.
// STAGE=1: BK=64, GL16 single-buffer. STAGE=0: BK=32 register-prefetch.
// SPLIT3: C column c -> segment c>>10 (Yq/Yk/Yv contiguous, 4M elems apart).
template<int RELU, int OUT_F32, int HAS_BIAS, int SPLIT3, int STAGE>
__global__ __launch_bounds__(256) void mfma_gemm(
    const u16* __restrict__ A, const u16* __restrict__ B,
    const float* __restrict__ bias, void* __restrict__ Cout,
    int M, int N, int K)
{
    __shared__ __align__(16) u16 As[8192];   // STAGE=1: [128][64]; STAGE=0: uses 4096
    __shared__ __align__(16) u16 Bs[8192];
    const int tid = threadIdx.x;
    const int wave = tid >> 6, lane = tid & 63;
    const int quad = lane >> 4, l16 = lane & 15;
    const int m0 = blockIdx.y << 7, n0 = blockIdx.x << 7;
    const int wm = (wave >> 1) << 6, wn = (wave & 1) << 6;

    f32x4 acc[4][4];
#pragma unroll
    for (int i = 0; i < 4; i++)
#pragma unroll
        for (int j = 0; j < 4; j++) acc[i][j] = (f32x4){0.f, 0.f, 0.f, 0.f};

    if (STAGE) {
        // ---- BK=64 GL16 path ----
        const int srow = tid >> 3;                                // 0..31
        const int csw = ((tid & 7) ^ ((tid >> 3) & 7)) << 3;      // src slot-XOR
        const u16* Ags = A + (size_t)(m0 + srow) * K + csw;
        const u16* Bgs = B + (size_t)(n0 + srow) * K + csw;
        const int rx = (l16 & 7) << 3;                            // read slot-XOR (elems)

        for (int k0 = 0; k0 < K; k0 += 64) {
            __syncthreads();                   // prior reads of LDS done
#pragma unroll
            for (int i = 0; i < 4; i++) {
                GL16(Ags + (size_t)(i * 32) * K + k0, &As[(i * 256 + tid) * 8]);
                GL16(Bgs + (size_t)(i * 32) * K + k0, &Bs[(i * 256 + tid) * 8]);
            }
            __syncthreads();                   // vmcnt(0) drain: tile resident

#pragma unroll
            for (int kk = 0; kk < 2; kk++) {
                bf16x8 af[4], bfr[4];
#pragma unroll
                for (int mi = 0; mi < 4; mi++)
                    af[mi] = *(const bf16x8*)(As + ((wm + mi * 16 + l16) << 6) +
                                              ((((kk * 4 + quad) << 3) ^ rx)));
#pragma unroll
                for (int ni = 0; ni < 4; ni++)
                    bfr[ni] = *(const bf16x8*)(Bs + ((wn + ni * 16 + l16) << 6) +
                                               ((((kk * 4 + quad) << 3) ^ rx)));
#pragma unroll
                for (int mi = 0; mi < 4; mi++)
#pragma unroll
                    for (int ni = 0; ni < 4; ni++)
                        acc[mi][ni] = __builtin_amdgcn_mfma_f32_16x16x32_bf16(
                            af[mi], bfr[ni], acc[mi][ni], 0, 0, 0);
            }
        }
    } else {
        // ---- BK=32 register-prefetch path (R14-proven) ----
        const int r0 = tid >> 2;
        const int csw = ((tid & 3) ^ ((r0 >> 1) & 3)) << 3;
        const u16* Ag0 = A + (size_t)(m0 + r0) * K + csw;
        const u16* Ag1 = A + (size_t)(m0 + r0 + 64) * K + csw;
        const u16* Bg0 = B + (size_t)(n0 + r0) * K + csw;
        const u16* Bg1 = B + (size_t)(n0 + r0 + 64) * K + csw;
        const int pb = ((quad ^ ((l16 >> 1) & 3)) << 3);

        uint4 a0 = *(const uint4*)(Ag0);
        uint4 a1 = *(const uint4*)(Ag1);
        uint4 b0 = *(const uint4*)(Bg0);
        uint4 b1 = *(const uint4*)(Bg1);

        for (int k0 = 0; k0 < K; k0 += 32) {
            __syncthreads();
            *(uint4*)(As + tid * 8)        = a0;
            *(uint4*)(As + 2048 + tid * 8) = a1;
            *(uint4*)(Bs + tid * 8)        = b0;
            *(uint4*)(Bs + 2048 + tid * 8) = b1;
            __syncthreads();

            if (k0 + 32 < K) {                // prefetch next tile
                a0 = *(const uint4*)(Ag0 + k0 + 32);
                a1 = *(const uint4*)(Ag1 + k0 + 32);
                b0 = *(const uint4*)(Bg0 + k0 + 32);
                b1 = *(const uint4*)(Bg1 + k0 + 32);
            }

            bf16x8 af[4], bfr[4];
#pragma unroll
            for (int mi = 0; mi < 4; mi++)
                af[mi] = *(const bf16x8*)(As + ((wm + mi * 16 + l16) << 5) + pb);
#pragma unroll
            for (int ni = 0; ni < 4; ni++)
                bfr[ni] = *(const bf16x8*)(Bs + ((wn + ni * 16 + l16) << 5) + pb);
#pragma unroll
            for (int mi = 0; mi < 4; mi++)
#pragma unroll
                for (int ni = 0; ni < 4; ni++)
                    acc[mi][ni] = __builtin_amdgcn_mfma_f32_16x16x32_bf16(
                        af[mi], bfr[ni], acc[mi][ni], 0, 0, 0);
        }
    }

    float bb[4];
#pragma unroll
    for (int ni = 0; ni < 4; ni++)
        bb[ni] = HAS_BIAS ? bias[n0 + wn + ni * 16 + l16] : 0.f;

#pragma unroll
    for (int mi = 0; mi < 4; mi++) {
#pragma unroll
        for (int ni = 0; ni < 4; ni++) {
            const int col = n0 + wn + ni * 16 + l16;
            const size_t cb = SPLIT3
                ? (((size_t)(col >> 10) << 22) + (size_t)(col & 1023))
                : (size_t)col;
#pragma unroll
            for (int r = 0; r < 4; r++) {
                const int row = m0 + wm + mi * 16 + quad * 4 + r;
                float v = acc[mi][ni][r] + bb[ni];
                if (RELU) v = fmaxf(v, 0.f);
                const size_t idx = SPLIT3 ? (cb + ((size_t)row << 10))
                                          : ((size_t)row * N + cb);
                if (OUT_F32) ((float*)Cout)[idx] = v;
                else ((u16*)Cout)[idx] = f2bf(v);
            }
        }
    }
}

// ---------------- scores strip kernel: QK^T/8 + rel-pos skew ----------------
// grid (16 s-strips, 64 bh). Block owns rows [s0,s0+64) of scores[bh] and
// loops t0 over 16 tiles of 64. 4 waves in a 2x2 (s,t) split.
// LDS = 53760 B exactly: the PROVEN 3-blocks/CU size (54016+ drops to 2).
__global__ __launch_bounds__(256) void qk_strip(
    const u16* __restrict__ Yq, const u16* __restrict__ Yk,
    const u16* __restrict__ relwT, u16* __restrict__ scores)
{
    // LDS: Ks [64][72] | Rw 2x[64][72] | Eb [64][132] | Ssh [64][72]
    __shared__ __align__(16) u16 lds[26880];          // 53760 B -> 3 blocks/CU
    u16* Ks  = lds;
    u16* Rw  = lds + 4608;
    u16* Eb  = lds + 13824;
    u16* Ssh = lds + 22272;

    const int tid = threadIdx.x;
    const int wave = tid >> 6, lane = tid & 63;
    const int quad = lane >> 4, l16 = lane & 15;
    const int ws = wave >> 1, wt = wave & 1;

    // XCD-aware swizzle: 1024 blocks, 8 XCDs -> contiguous 128-block chunks
    const int linb = blockIdx.y * 16 + blockIdx.x;
    const int swz = (linb & 7) * 128 + (linb >> 3);
    const int si = swz & 15, bh = swz >> 4;
    const int b = bh >> 4, h = bh & 15;
    const int s0 = si << 6;
    const int qb0 = 15 - si;                   // U0(iter0) >> 6
    const int tau0 = 2 + wt * 2 - ws * 2;      // wave's first c-tile (of 16)

    // Q fragments (rows = wave's 32 s, k = dh=64 in two 32-chunks)
    bf16x8 qf[2][2];
#pragma unroll
    for (int mi = 0; mi < 2; mi++)
#pragma unroll
        for (int kk = 0; kk < 2; kk++)
            qf[mi][kk] = *(const bf16x8*)(Yq +
                ((size_t)(b * 1024 + s0 + ws * 32 + mi * 16 + l16) << 10) +
                h * 64 + kk * 32 + quad * 8);

    // staging thread map: row r (0..63), 16-col chunk cq
    const int r = tid >> 2, cq = (tid & 3) << 4;
    const u16* Kg = Yk + ((size_t)(b * 1024 + r) << 10) + h * 64 + cq;
    const u16* Rg = relwT + ((size_t)bh << 16) + cq;

    uint4 kp0, kp1, rp0, rp1, ri0, ri1;
    kp0 = *(const uint4*)(Kg);
    kp1 = *(const uint4*)(Kg + 8);
    {   // initial Rw half: u in [960-s0, 1024-s0)  (always valid rows)
        const u16* p = Rg + ((size_t)(960 - s0 + r) << 6);
        ri0 = *(const uint4*)p; ri1 = *(const uint4*)(p + 8);
    }
    {   // half staged at iter 0: u in [1024-s0, 1088-s0), zero-fill u>=1024
        const int u = 1024 - s0 + r;
        uint4 z = {0, 0, 0, 0};
        rp0 = z; rp1 = z;
        if (u < 1024) {
            const u16* p = Rg + ((size_t)u << 6);
            rp0 = *(const uint4*)p; rp1 = *(const uint4*)(p + 8);
        }
    }

    for (int i = 0; i < 16; i++) {
        const int t0 = i << 6;
        __syncthreads();                       // prev-iter LDS readers done
        *(uint4*)(Ks + r * 72 + cq)     = kp0;
        *(uint4*)(Ks + r * 72 + cq + 8) = kp1;
        if (i == 0) {
            u16* hb = Rw + (qb0 & 1) * 4608;
            *(uint4*)(hb + r * 72 + cq)     = ri0;
            *(uint4*)(hb + r * 72 + cq + 8) = ri1;
        }
        if (i <= si) {
            u16* hb = Rw + ((qb0 + i + 1) & 1) * 4608;
            *(uint4*)(hb + r * 72 + cq)     = rp0;
            *(uint4*)(hb + r * 72 + cq + 8) = rp1;
        }
        __syncthreads();                       // staged data visible

        // prefetch next tile into regs (overlaps with MFMA below)
        if (i + 1 < 16) {
            const u16* p = Kg + ((size_t)(i + 1) << 16);
            kp0 = *(const uint4*)p; kp1 = *(const uint4*)(p + 8);
        }
        if (i + 1 <= si) {
            const int u = 1024 - s0 + ((i + 1) << 6) + r;
            uint4 z = {0, 0, 0, 0};
            rp0 = z; rp1 = z;
            if (u < 1024) {
                const u16* p = Rg + ((size_t)u << 6);
                rp0 = *(const uint4*)p; rp1 = *(const uint4*)(p + 8);
            }
        }

        // ---- QK^T quadrant: 2mi x 2nj, K=64 ----
        f32x4 aqk[2][2];
#pragma unroll
        for (int mi = 0; mi < 2; mi++)
#pragma unroll
            for (int nj = 0; nj < 2; nj++) aqk[mi][nj] = (f32x4){0.f, 0.f, 0.f, 0.f};
#pragma unroll
        for (int kk = 0; kk < 2; kk++)
#pragma unroll
            for (int nj = 0; nj < 2; nj++) {
                bf16x8 kb = *(const bf16x8*)(Ks + (wt * 32 + nj * 16 + l16) * 72 +
                                             kk * 32 + quad * 8);
#pragma unroll
                for (int mi = 0; mi < 2; mi++)
                    aqk[mi][nj] = __builtin_amdgcn_mfma_f32_16x16x32_bf16(
                        qf[mi][kk], kb, aqk[mi][nj], 0, 0, 0);
            }

        const int eact = (i <= si);
        if (eact) {
            // ---- E^T tiles: rows=u (4 tiles from tau0), cols=s (2 mi) ----
            const int qb = qb0 + i;
            f32x4 ae[4][2];
#pragma unroll
            for (int uj = 0; uj < 4; uj++)
#pragma unroll
                for (int mi = 0; mi < 2; mi++) ae[uj][mi] = (f32x4){0.f, 0.f, 0.f, 0.f};
#pragma unroll
            for (int kk = 0; kk < 2; kk++)
#pragma unroll
                for (int uj = 0; uj < 4; uj++) {
                    const int tau = tau0 + uj;
                    const u16* hp = Rw + ((qb + (tau >> 2)) & 1) * 4608;
                    bf16x8 ra = *(const bf16x8*)(hp + ((tau & 3) * 16 + l16) * 72 +
                                                 kk * 32 + quad * 8);
#pragma unroll
                    for (int mi = 0; mi < 2; mi++)
                        ae[uj][mi] = __builtin_amdgcn_mfma_f32_16x16x32_bf16(
                            ra, qf[mi][kk], ae[uj][mi], 0, 0, 0);
                }
            // pack 4 consecutive-u values -> b64 into row-major Eb[s][c]
#pragma unroll
            for (int uj = 0; uj < 4; uj++)
#pragma unroll
                for (int mi = 0; mi < 2; mi++) {
                    const int scol = ws * 32 + mi * 16 + l16;
                    const int cb = (tau0 + uj) * 16 + quad * 4;
                    uint2 pk;
                    pk.x = (u32)f2bf(ae[uj][mi][0]) | ((u32)f2bf(ae[uj][mi][1]) << 16);
                    pk.y = (u32)f2bf(ae[uj][mi][2]) | ((u32)f2bf(ae[uj][mi][3]) << 16);
                    *(uint2*)(Eb + scol * 132 + cb) = pk;
                }
        }

        // ---- combine + stage to Ssh (wave-local quadrant) ----
#pragma unroll
        for (int mi = 0; mi < 2; mi++)
#pragma unroll
            for (int nj = 0; nj < 2; nj++)
#pragma unroll
                for (int rr = 0; rr < 4; rr++) {
                    const int sl = ws * 32 + mi * 16 + quad * 4 + rr;
                    const int tl = wt * 32 + nj * 16 + l16;
                    float e = 0.f;
                    if (eact) e = bf2f(Eb[sl * 131 + 63 + tl]);  // = [sl][63+tl-sl]
                    Ssh[sl * 72 + tl] = f2bf(aqk[mi][nj][rr] * 0.125f + e);
                }

        // ---- coalesced write of the wave's own 32x32 quadrant ----
        {
            const int row = ws * 32 + (lane >> 1);
            const int col = wt * 32 + ((lane & 1) << 4);
            uint4 v0 = *(const uint4*)(Ssh + row * 72 + col);
            uint4 v1 = *(const uint4*)(Ssh + row * 72 + col + 8);
            u16* op = scores + (((size_t)bh * 1024 + s0 + row) << 10) + t0 + col;
            *(uint4*)op = v0;
            *(uint4*)(op + 8) = v1;
        }
    }
}

// ------------- fused batch-softmax + PV, split over t-halves ---------------
// Opart[th][bh][s][d] = sum_{t in half} softmax_b(scraw)[bh][s][t]*YvT[bh][d][t]
// grid (256, 2) = (16h x 16 s-tiles) x (t-half). Each block = R16-exact
// pv_smx over 8 t-chunks: softmax ONCE per fragment (partitioned, not
// duplicated -- R20's mistake), acc[4][4]. 2 blocks/CU = 8 waves/CU.
__global__ __launch_bounds__(256) void pv_smx(
    const u16* __restrict__ scraw, const u16* __restrict__ YvT,
    float* __restrict__ O0, float* __restrict__ O1)
{
    __shared__ __align__(16) u16 Vt[18432];    // V[4][64][72] = 36 KB
    const int tid = threadIdx.x;
    const int w = tid >> 6, lane = tid & 63;
    const int quad = lane >> 4, l16 = lane & 15;
    const int th = blockIdx.y;                 // t-half
    const int tbase = th << 9;                 // 0 or 512

    // h-major XCD swizzle: XCD k gets h in {2k,2k+1} -> V panels L2-resident
    const int bid = blockIdx.x;
    const int swz = (bid & 7) * 32 + (bid >> 3);
    const int h = swz >> 4, si = swz & 15;
    const int s0 = si << 6;

    // per-lane direct P fragment base (includes t-half offset)
    const u16* Pl = scraw + ((size_t)(h * 1024 + s0 + w * 16 + l16) << 10) +
                    tbase + quad * 8;
    // V staging map
    const int sr0 = tid >> 3, sc0 = (tid & 7) << 3;
    const u16* Vg = YvT + ((size_t)h << 16) + ((size_t)sr0 << 10) + tbase + sc0;

    f32x4 acc[4][4];
#pragma unroll
    for (int b = 0; b < 4; b++)
#pragma unroll
        for (int j = 0; j < 4; j++) acc[b][j] = (f32x4){0.f, 0.f, 0.f, 0.f};

    u32x4 pc[4][2], pn[4][2], vc[4][2], vn[4][2];
#pragma unroll
    for (int b = 0; b < 4; b++) {
        pc[b][0] = *(const u32x4*)(Pl + ((size_t)b << 24));
        pc[b][1] = *(const u32x4*)(Pl + ((size_t)b << 24) + 32);
        vc[b][0] = *(const u32x4*)(Vg + ((size_t)b << 20));
        vc[b][1] = *(const u32x4*)(Vg + ((size_t)b << 20) + (32 << 10));
    }

    for (int t0 = 0; t0 < 512; t0 += 64) {
        __syncthreads();
#pragma unroll
        for (int b = 0; b < 4; b++) {
            *(u32x4*)(Vt + b * 4608 + sr0 * 72 + sc0)        = vc[b][0];
            *(u32x4*)(Vt + b * 4608 + (sr0 + 32) * 72 + sc0) = vc[b][1];
        }
        __syncthreads();

        const int more = (t0 + 64 < 512);
        if (more) {                            // prefetch next chunk (regs)
#pragma unroll
            for (int b = 0; b < 4; b++) {
                pn[b][0] = *(const u32x4*)(Pl + ((size_t)b << 24) + t0 + 64);
                pn[b][1] = *(const u32x4*)(Pl + ((size_t)b << 24) + t0 + 96);
                vn[b][0] = *(const u32x4*)(Vg + ((size_t)b << 20) + t0 + 64);
                vn[b][1] = *(const u32x4*)(Vg + ((size_t)b << 20) + (32 << 10) + t0 + 64);
            }
        }

#pragma unroll
        for (int kk = 0; kk < 2; kk++) {
            // in-register 4-way batch softmax on the raw fragment words
            u32x4 aw[4];
#pragma unroll
            for (int j = 0; j < 4; j++) {
                float x0[4], x1[4];
#pragma unroll
                for (int b = 0; b < 4; b++) {
                    const u32 wd = pc[b][kk][j];
                    x0[b] = __uint_as_float(wd << 16);
                    x1[b] = __uint_as_float(wd & 0xffff0000u);
                }
                const float m0 = fmaxf(fmaxf(x0[0], x0[1]), fmaxf(x0[2], x0[3]));
                const float m1 = fmaxf(fmaxf(x1[0], x1[1]), fmaxf(x1[2], x1[3]));
                float s0v = 0.f, s1v = 0.f;
#pragma unroll
                for (int b = 0; b < 4; b++) {
                    x0[b] = __expf(x0[b] - m0); s0v += x0[b];
                    x1[b] = __expf(x1[b] - m1); s1v += x1[b];
                }
                const float r0 = 1.f / s0v, r1 = 1.f / s1v;
#pragma unroll
                for (int b = 0; b < 4; b++)
                    aw[b][j] = (u32)f2bf(x0[b] * r0) | ((u32)f2bf(x1[b] * r1) << 16);
            }
#pragma unroll
            for (int b = 0; b < 4; b++) {
                const bf16x8 af = __builtin_bit_cast(bf16x8, aw[b]);
#pragma unroll
                for (int nj = 0; nj < 4; nj++) {
                    bf16x8 bv = *(const bf16x8*)(Vt + b * 4608 + (nj * 16 + l16) * 72 +
                                                 kk * 32 + quad * 8);
                    acc[b][nj] = __builtin_amdgcn_mfma_f32_16x16x32_bf16(
                        af, bv, acc[b][nj], 0, 0, 0);
                }
            }
        }

        if (more) {
#pragma unroll
            for (int b = 0; b < 4; b++) {
                pc[b][0] = pn[b][0]; pc[b][1] = pn[b][1];
                vc[b][0] = vn[b][0]; vc[b][1] = vn[b][1];
            }
        }
    }

    float* Op = th ? O1 : O0;
#pragma unroll
    for (int b = 0; b < 4; b++)
#pragma unroll
        for (int nj = 0; nj < 4; nj++)
#pragma unroll
            for (int rr = 0; rr < 4; rr++) {
                const int row = s0 + w * 16 + quad * 4 + rr;
                Op[((((size_t)(b * 16 + h) << 10) + row) << 6) + nj * 16 + l16] =
                    acc[b][nj][rr];
            }
}

// ------------- out = LN(A + Bf [+ Bf2]) * g + beta -------------------------
template<int DTA, int OUT_F32, int TWOB>
__global__ __launch_bounds__(256) void add_ln(
    const void* __restrict__ A, const float* __restrict__ Bf,
    const float* __restrict__ Bf2,
    const float* __restrict__ g, const float* __restrict__ beta,
    void* __restrict__ out)
{
    const int row = blockIdx.x;
    const int tid = threadIdx.x;
    const size_t base = (size_t)row * 1024;
    float v[4], s1 = 0.f, s2 = 0.f;
#pragma unroll
    for (int k = 0; k < 4; k++) {
        const int c = k * 256 + tid;
        float t = load1<DTA>(A, base + c) + Bf[base + c];
        if (TWOB) t += Bf2[base + c];
        v[k] = t; s1 += t; s2 += t * t;
    }
#pragma unroll
    for (int m = 1; m < 64; m <<= 1) {
        s1 += __shfl_xor(s1, m, 64);
        s2 += __shfl_xor(s2, m, 64);
    }
    __shared__ float red[8];
    if ((tid & 63) == 0) { red[(tid >> 6) * 2] = s1; red[(tid >> 6) * 2 + 1] = s2; }
    __syncthreads();
    s1 = red[0] + red[2] + red[4] + red[6];
    s2 = red[1] + red[3] + red[5] + red[7];
    const float mean = s1 * (1.f / 1024.f);
    const float var = s2 * (1.f / 1024.f) - mean * mean;
    const float rstd = rsqrtf(var + 1e-5f);
#pragma unroll
    for (int k = 0; k < 4; k++) {
        const int c = k * 256 + tid;
        float o = (v[k] - mean) * rstd * g[c] + beta[c];
        if (OUT_F32) ((float*)out)[base + c] = o;
        else ((u16*)out)[base + c] = f2bf(o);
    }
}

// ---------------------------------------------------------------------------
extern "C" void kernel_launch(void* const* d_in, const int* in_sizes, int n_in,
                              void* d_out, int out_size, void* d_ws, size_t ws_size,
                              hipStream_t stream)
{
    const float* x    = (const float*)d_in[0];
    const float* wq   = (const float*)d_in[1];
    const float* wk   = (const float*)d_in[2];
    const float* wv   = (const float*)d_in[3];
    const float* relw = (const float*)d_in[4];
    const float* g1   = (const float*)d_in[5];
    const float* be1  = (const float*)d_in[6];
    const float* g2   = (const float*)d_in[7];
    const float* be2  = (const float*)d_in[8];
    const float* w1   = (const float*)d_in[9];
    const float* b1   = (const float*)d_in[10];
    const float* w2   = (const float*)d_in[11];
    const float* b2   = (const float*)d_in[12];

    const size_t NEEDED = ((size_t)224 << 20);
    if (ws_size < NEEDED) {
        sentinel_ws<<<dim3(1024), dim3(256), 0, stream>>>((float*)d_out, (u32)out_size);
        return;
    }

    char* ws = (char*)d_ws;
    float* O0    = (float*)(ws);
    u16*   relwT = (u16*)(ws);                                  // dies before pv
    u16*   Yq    = (u16*)(ws + ((size_t)16 << 20));             // Yq/Yk/Yv contig
    u16*   Yk    = (u16*)(ws + ((size_t)24 << 20));
    u16*   Yv    = (u16*)(ws + ((size_t)32 << 20));
    u16*   h1    = (u16*)(ws + ((size_t)40 << 20));
    u16*   ffn1  = (u16*)(ws + ((size_t)48 << 20));
    float* O1    = (float*)(ws + ((size_t)48 << 20));           // dies at add_ln
    float* ffn2  = (float*)(ws + ((size_t)80 << 20));
    u16*   YvT   = (u16*)(ws + ((size_t)80 << 20));             // dies before ffn2
    u16*   sc    = (u16*)(ws + ((size_t)96 << 20));
    u16*   xb    = (u16*)(ws + ((size_t)96 << 20));             // pre-qk
    u16*   wqb   = (u16*)(ws + ((size_t)104 << 20));            // wq|wk|wv contig
    u16*   wkb   = (u16*)(ws + ((size_t)106 << 20));
    u16*   wvb   = (u16*)(ws + ((size_t)108 << 20));
    u16*   w1b   = (u16*)(ws + ((size_t)96 << 20));             // post-pv
    u16*   w2b   = (u16*)(ws + ((size_t)104 << 20));

    dim3 blk(256);
    const u32 M4 = 4u << 20, M1 = 1u << 20;

    // fp32 -> bf16 staging + relw transpose
    cvt_f32_bf16<<<dim3(M4 / 1024), blk, 0, stream>>>(x,  xb,  M4);
    cvt_f32_bf16<<<dim3(M1 / 1024), blk, 0, stream>>>(wq, wqb, M1);
    cvt_f32_bf16<<<dim3(M1 / 1024), blk, 0, stream>>>(wk, wkb, M1);
    cvt_f32_bf16<<<dim3(M1 / 1024), blk, 0, stream>>>(wv, wvb, M1);
    relw_tr<<<dim3(16, 64), blk, 0, stream>>>(relw, relwT);

    // fused QKV projection: B=[wq;wk;wv] (3072x1024), C split into Yq/Yk/Yv
    // 768 blocks = 3/CU -> BK=64 GL16 schedule (STAGE=1)
    mfma_gemm<0,0,0,1,1><<<dim3(24, 32), blk, 0, stream>>>(
        xb, wqb, nullptr, Yq, 4096, 3072, 1024);
    yv_tr<<<dim3(16, 64), blk, 0, stream>>>(Yv, YvT);

    // scores strip kernel (raw) + fused batch-softmax+PV (t-half split)
    qk_strip<<<dim3(16, 64), blk, 0, stream>>>(Yq, Yk, relwT, sc);
    pv_smx<<<dim3(256, 2), blk, 0, stream>>>(sc, YvT, O0, O1);

    // h1 = LN(x + O0 + O1)
    add_ln<1,0,1><<<dim3(4096), blk, 0, stream>>>(x, O0, O1, g1, be1, h1);

    // FFN weights -> bf16 (scores region dead after pv)
    cvt_f32_bf16<<<dim3(M4 / 1024), blk, 0, stream>>>(w1, w1b, M4);
    cvt_f32_bf16<<<dim3(M4 / 1024), blk, 0, stream>>>(w2, w2b, M4);

    // FFN (MFMA): ffn1 1024 blocks = 4/CU -> STAGE=1 BK=64; ffn2 256 = 1/CU -> STAGE=0
    mfma_gemm<1,0,1,0,1><<<dim3(32, 32), blk, 0, stream>>>(h1, w1b, b1, ffn1, 4096, 4096, 1024);
    mfma_gemm<0,1,1,0,0><<<dim3(8, 32), blk, 0, stream>>>(ffn1, w2b, b2, ffn2, 4096, 1024, 4096);

    // out = LN(h1 + ffn) -> f32
    add_ln<0,1,0><<<dim3(4096), blk, 0, stream>>>(h1, ffn2, nullptr, g2, be2, (float*)d_out);
}

// Round 13
// 412.879 us; speedup vs baseline: 1.0773x; 1.0326x over previous
//
#include <hip/hip_runtime.h>

// ---------------------------------------------------------------------------
// EncoderLayer: S=1024, B=4, D=1024, H=16, dh=64, DFF=4096. fp32 I/O.
// R22: R21 base + ffn2 K-split x2 (discriminating experiment: occupancy vs
// fetch-wall for the ~490TF GEMM plateau).
//  - ffn2 (M4096,N1024,K4096) was 256 blocks = 1 blk/CU and (by FLOP parity
//    with ffn1) ~65-70us just under the top-5 cutoff. Split K into halves:
//    grid (8,32,2), 512 blocks = 2 blk/CU, each half K=2048 (lda=4096).
//    Partial f32 outputs ffn2a/ffn2b; bias added in half 0 only.
//  - final add_ln -> TWOB=1 folds ffn2a+ffn2b (R21-proven pattern).
//  - mfma_gemm gains lda param + SPLITK flag (blockIdx.z selects K-offset
//    and output buffer). All other call sites lda=K, z=1.
// Everything else byte-exact R21 (= R16 champion + pv t-split).
//
// Workspace map (224 MB):
//  [0,16M)    O0 f32  (first 8MB doubles as relwT bf16 until pv)
//  [16M,24M) Yq bf16  [24M,32M) Yk  [32M,40M) Yv   (contiguous for SPLIT3)
//  [40M,48M)  h1 bf16  [48M,80M) ffn1 bf16 (first 16MB doubles as O1 f32)
//  [80M,96M)  ffn2a f32 (first 8MB doubles as YvT bf16 until ffn2 GEMM)
//  [96M,224M) scores bf16 (RAW; consumed by pv_smx)
//    overlap (pre-qk):  xb@96M(8MB) wqb@104M wkb@106M wvb@108M (contiguous B)
//    overlap (post-pv): w1b@96M(8MB) w2b@104M(8MB) ffn2b@112M(16MB f32)
// ---------------------------------------------------------------------------

typedef unsigned short u16;
typedef unsigned int u32;
typedef __attribute__((ext_vector_type(4))) float f32x4;
typedef __attribute__((ext_vector_type(8))) short bf16x8;
typedef __attribute__((ext_vector_type(4))) u32 u32x4;

__device__ __forceinline__ float bf2f(u16 u) { return __uint_as_float(((u32)u) << 16); }
__device__ __forceinline__ u16 f2bf(float f) {
    u32 u = __float_as_uint(f);
    u += 0x7fffu + ((u >> 16) & 1u);   // RNE
    return (u16)(u >> 16);
}
template<int DT>
__device__ __forceinline__ float load1(const void* P, size_t idx) {
    return (DT == 0) ? bf2f(((const u16*)P)[idx]) : ((const float*)P)[idx];
}

// async global->LDS DMA, 16B per lane. LDS dest linear in lane order
// (wave-uniform base + lane*16); swizzle lives on the GLOBAL address.
#define GL16(gp, lp)                                                        \
    __builtin_amdgcn_global_load_lds(                                       \
        (const __attribute__((address_space(1))) void*)(gp),                \
        (__attribute__((address_space(3))) void*)(lp), 16, 0, 0)

__global__ __launch_bounds__(256) void sentinel_ws(float* out, u32 n)
{
    for (u32 i = blockIdx.x * 256 + threadIdx.x; i < n; i += gridDim.x * 256) out[i] = 31000.0f;
}

// ---------------- fp32 -> bf16 bulk convert (n mult of 4) ------------------
__global__ __launch_bounds__(256) void cvt_f32_bf16(const float* __restrict__ s,
                                                    u16* __restrict__ d, u32 n)
{
    u32 i = (blockIdx.x * 256 + threadIdx.x) * 4;
    if (i >= n) return;
    float4 v = *(const float4*)(s + i);
    uint2 pk;
    pk.x = (u32)f2bf(v.x) | ((u32)f2bf(v.y) << 16);
    pk.y = (u32)f2bf(v.z) | ((u32)f2bf(v.w) << 16);
    *(uint2*)(d + i) = pk;
}

// ------- relwT[bh][u][d] (bf16) = relw[bh][d][u] (fp32) --------------------
__global__ __launch_bounds__(256) void relw_tr(const float* __restrict__ relw,
                                               u16* __restrict__ relwT)
{
    __shared__ __align__(16) float T[64][68];
    const int tid = threadIdx.x;
    const int bh = blockIdx.y;
    const int u0 = blockIdx.x << 6;
    {
        const int d = tid >> 2, uq = (tid & 3) << 4;
        const float* rp = relw + (size_t)bh * 65536 + (size_t)d * 1024 + u0 + uq;
#pragma unroll
        for (int i = 0; i < 4; i++)
            *(float4*)&T[d][uq + i * 4] = *(const float4*)(rp + i * 4);
    }
    __syncthreads();
    {
        const int u = tid >> 2, dq = (tid & 3) << 4;
        u32 pk[8];
#pragma unroll
        for (int p = 0; p < 8; p++) {
            float a = T[dq + p * 2][u], b = T[dq + p * 2 + 1][u];
            pk[p] = (u32)f2bf(a) | ((u32)f2bf(b) << 16);
        }
        u16* op = relwT + ((size_t)(bh * 1024 + u0 + u) << 6) + dq;
        *(uint4*)op = *(uint4*)&pk[0];
        *(uint4*)(op + 8) = *(uint4*)&pk[4];
    }
}

// ------- YvT[bh][d][t] (bf16) = Yv[(b*1024+t)*1024 + h*64+d] ---------------
__global__ __launch_bounds__(256) void yv_tr(const u16* __restrict__ Yv,
                                             u16* __restrict__ YvT)
{
    __shared__ __align__(16) u16 T[64][72];
    const int tid = threadIdx.x;
    const int bh = blockIdx.y, b = bh >> 4, h = bh & 15;
    const int t0 = blockIdx.x << 6;
    {
        const int r = tid >> 2, cq = (tid & 3) << 4;
        const u16* p = Yv + ((size_t)(b * 1024 + t0 + r) << 10) + h * 64 + cq;
        *(uint4*)&T[r][cq] = *(const uint4*)p;
        *(uint4*)&T[r][cq + 8] = *(const uint4*)(p + 8);
    }
    __syncthreads();
    {
        const int d = tid >> 2, tq = (tid & 3) << 4;
        u16 vals[16];
#pragma unroll
        for (int p = 0; p < 16; p++) vals[p] = T[tq + p][d];
        u16* op = YvT + (((size_t)bh * 64 + d) << 10) + t0 + tq;
        *(uint4*)op = ((uint4*)vals)[0];
        *(uint4*)(op + 8) = ((uint4*)vals)[1];
    }
}

// --------------- MFMA GEMM: C[M,N] = act(A[M,K] @ B[N,K]^T + bias) ---------
// 128x128 tile, 4 waves, 4x4 mfma_f32_16x16x32_bf16 per wave.
// STAGE=1: BK=64, GL16 single-buffer. STAGE=0: BK=32 register-prefetch.
// SPLIT3: C column c -> segment c>>10 (Yq/Yk/Yv contiguous, 4M elems apart).
// SPLITK: blockIdx.z selects K-offset (z*K within rows of stride lda) and
// output buffer (Cout / Cout2); bias applied in z==0 only.
template<int RELU, int OUT_F32, int HAS_BIAS, int SPLIT3, int STAGE, int SPLITK>
__global__ __launch_bounds__(256) void mfma_gemm(
    const u16* __restrict__ A, const u16* __restrict__ B,
    const float* __restrict__ bias, void* __restrict__ Cout,
    void* __restrict__ Cout2, int M, int N, int K, int lda)
{
    __shared__ __align__(16) u16 As[8192];   // STAGE=1: [128][64]; STAGE=0: uses 4096
    __shared__ __align__(16) u16 Bs[8192];
    const int tid = threadIdx.x;
    const int wave = tid >> 6, lane = tid & 63;
    const int quad = lane >> 4, l16 = lane & 15;
    const int m0 = blockIdx.y << 7, n0 = blockIdx.x << 7;
    const int wm = (wave >> 1) << 6, wn = (wave & 1) << 6;
    const int koff = SPLITK ? blockIdx.z * K : 0;

    f32x4 acc[4][4];
#pragma unroll
    for (int i = 0; i < 4; i++)
#pragma unroll
        for (int j = 0; j < 4; j++) acc[i][j] = (f32x4){0.f, 0.f, 0.f, 0.f};

    if (STAGE) {
        // ---- BK=64 GL16 path ----
        const int srow = tid >> 3;                                // 0..31
        const int csw = ((tid & 7) ^ ((tid >> 3) & 7)) << 3;      // src slot-XOR
        const u16* Ags = A + (size_t)(m0 + srow) * lda + koff + csw;
        const u16* Bgs = B + (size_t)(n0 + srow) * lda + koff + csw;
        const int rx = (l16 & 7) << 3;                            // read slot-XOR (elems)

        for (int k0 = 0; k0 < K; k0 += 64) {
            __syncthreads();                   // prior reads of LDS done
#pragma unroll
            for (int i = 0; i < 4; i++) {
                GL16(Ags + (size_t)(i * 32) * lda + k0, &As[(i * 256 + tid) * 8]);
                GL16(Bgs + (size_t)(i * 32) * lda + k0, &Bs[(i * 256 + tid) * 8]);
            }
            __syncthreads();                   // vmcnt(0) drain: tile resident

#pragma unroll
            for (int kk = 0; kk < 2; kk++) {
                bf16x8 af[4], bfr[4];
#pragma unroll
                for (int mi = 0; mi < 4; mi++)
                    af[mi] = *(const bf16x8*)(As + ((wm + mi * 16 + l16) << 6) +
                                              ((((kk * 4 + quad) << 3) ^ rx)));
#pragma unroll
                for (int ni = 0; ni < 4; ni++)
                    bfr[ni] = *(const bf16x8*)(Bs + ((wn + ni * 16 + l16) << 6) +
                                               ((((kk * 4 + quad) << 3) ^ rx)));
#pragma unroll
                for (int mi = 0; mi < 4; mi++)
#pragma unroll
                    for (int ni = 0; ni < 4; ni++)
                        acc[mi][ni] = __builtin_amdgcn_mfma_f32_16x16x32_bf16(
                            af[mi], bfr[ni], acc[mi][ni], 0, 0, 0);
            }
        }
    } else {
        // ---- BK=32 register-prefetch path (R14-proven) ----
        const int r0 = tid >> 2;
        const int csw = ((tid & 3) ^ ((r0 >> 1) & 3)) << 3;
        const u16* Ag0 = A + (size_t)(m0 + r0) * lda + koff + csw;
        const u16* Ag1 = A + (size_t)(m0 + r0 + 64) * lda + koff + csw;
        const u16* Bg0 = B + (size_t)(n0 + r0) * lda + koff + csw;
        const u16* Bg1 = B + (size_t)(n0 + r0 + 64) * lda + koff + csw;
        const int pb = ((quad ^ ((l16 >> 1) & 3)) << 3);

        uint4 a0 = *(const uint4*)(Ag0);
        uint4 a1 = *(const uint4*)(Ag1);
        uint4 b0 = *(const uint4*)(Bg0);
        uint4 b1 = *(const uint4*)(Bg1);

        for (int k0 = 0; k0 < K; k0 += 32) {
            __syncthreads();
            *(uint4*)(As + tid * 8)        = a0;
            *(uint4*)(As + 2048 + tid * 8) = a1;
            *(uint4*)(Bs + tid * 8)        = b0;
            *(uint4*)(Bs + 2048 + tid * 8) = b1;
            __syncthreads();

            if (k0 + 32 < K) {                // prefetch next tile
                a0 = *(const uint4*)(Ag0 + k0 + 32);
                a1 = *(const uint4*)(Ag1 + k0 + 32);
                b0 = *(const uint4*)(Bg0 + k0 + 32);
                b1 = *(const uint4*)(Bg1 + k0 + 32);
            }

            bf16x8 af[4], bfr[4];
#pragma unroll
            for (int mi = 0; mi < 4; mi++)
                af[mi] = *(const bf16x8*)(As + ((wm + mi * 16 + l16) << 5) + pb);
#pragma unroll
            for (int ni = 0; ni < 4; ni++)
                bfr[ni] = *(const bf16x8*)(Bs + ((wn + ni * 16 + l16) << 5) + pb);
#pragma unroll
            for (int mi = 0; mi < 4; mi++)
#pragma unroll
                for (int ni = 0; ni < 4; ni++)
                    acc[mi][ni] = __builtin_amdgcn_mfma_f32_16x16x32_bf16(
                        af[mi], bfr[ni], acc[mi][ni], 0, 0, 0);
        }
    }

    const int addb = HAS_BIAS && (!SPLITK || blockIdx.z == 0);
    float bb[4];
#pragma unroll
    for (int ni = 0; ni < 4; ni++)
        bb[ni] = addb ? bias[n0 + wn + ni * 16 + l16] : 0.f;

    void* Cw = (SPLITK && blockIdx.z) ? Cout2 : Cout;
#pragma unroll
    for (int mi = 0; mi < 4; mi++) {
#pragma unroll
        for (int ni = 0; ni < 4; ni++) {
            const int col = n0 + wn + ni * 16 + l16;
            const size_t cb = SPLIT3
                ? (((size_t)(col >> 10) << 22) + (size_t)(col & 1023))
                : (size_t)col;
#pragma unroll
            for (int r = 0; r < 4; r++) {
                const int row = m0 + wm + mi * 16 + quad * 4 + r;
                float v = acc[mi][ni][r] + bb[ni];
                if (RELU) v = fmaxf(v, 0.f);
                const size_t idx = SPLIT3 ? (cb + ((size_t)row << 10))
                                          : ((size_t)row * N + cb);
                if (OUT_F32) ((float*)Cw)[idx] = v;
                else ((u16*)Cw)[idx] = f2bf(v);
            }
        }
    }
}

// ---------------- scores strip kernel: QK^T/8 + rel-pos skew ----------------
// grid (16 s-strips, 64 bh). Block owns rows [s0,s0+64) of scores[bh] and
// loops t0 over 16 tiles of 64. 4 waves in a 2x2 (s,t) split.
// LDS = 53760 B exactly: the PROVEN 3-blocks/CU size (54016+ drops to 2).
__global__ __launch_bounds__(256) void qk_strip(
    const u16* __restrict__ Yq, const u16* __restrict__ Yk,
    const u16* __restrict__ relwT, u16* __restrict__ scores)
{
    // LDS: Ks [64][72] | Rw 2x[64][72] | Eb [64][132] | Ssh [64][72]
    __shared__ __align__(16) u16 lds[26880];          // 53760 B -> 3 blocks/CU
    u16* Ks  = lds;
    u16* Rw  = lds + 4608;
    u16* Eb  = lds + 13824;
    u16* Ssh = lds + 22272;

    const int tid = threadIdx.x;
    const int wave = tid >> 6, lane = tid & 63;
    const int quad = lane >> 4, l16 = lane & 15;
    const int ws = wave >> 1, wt = wave & 1;

    // XCD-aware swizzle: 1024 blocks, 8 XCDs -> contiguous 128-block chunks
    const int linb = blockIdx.y * 16 + blockIdx.x;
    const int swz = (linb & 7) * 128 + (linb >> 3);
    const int si = swz & 15, bh = swz >> 4;
    const int b = bh >> 4, h = bh & 15;
    const int s0 = si << 6;
    const int qb0 = 15 - si;                   // U0(iter0) >> 6
    const int tau0 = 2 + wt * 2 - ws * 2;      // wave's first c-tile (of 16)

    // Q fragments (rows = wave's 32 s, k = dh=64 in two 32-chunks)
    bf16x8 qf[2][2];
#pragma unroll
    for (int mi = 0; mi < 2; mi++)
#pragma unroll
        for (int kk = 0; kk < 2; kk++)
            qf[mi][kk] = *(const bf16x8*)(Yq +
                ((size_t)(b * 1024 + s0 + ws * 32 + mi * 16 + l16) << 10) +
                h * 64 + kk * 32 + quad * 8);

    // staging thread map: row r (0..63), 16-col chunk cq
    const int r = tid >> 2, cq = (tid & 3) << 4;
    const u16* Kg = Yk + ((size_t)(b * 1024 + r) << 10) + h * 64 + cq;
    const u16* Rg = relwT + ((size_t)bh << 16) + cq;

    uint4 kp0, kp1, rp0, rp1, ri0, ri1;
    kp0 = *(const uint4*)(Kg);
    kp1 = *(const uint4*)(Kg + 8);
    {   // initial Rw half: u in [960-s0, 1024-s0)  (always valid rows)
        const u16* p = Rg + ((size_t)(960 - s0 + r) << 6);
        ri0 = *(const uint4*)p; ri1 = *(const uint4*)(p + 8);
    }
    {   // half staged at iter 0: u in [1024-s0, 1088-s0), zero-fill u>=1024
        const int u = 1024 - s0 + r;
        uint4 z = {0, 0, 0, 0};
        rp0 = z; rp1 = z;
        if (u < 1024) {
            const u16* p = Rg + ((size_t)u << 6);
            rp0 = *(const uint4*)p; rp1 = *(const uint4*)(p + 8);
        }
    }

    for (int i = 0; i < 16; i++) {
        const int t0 = i << 6;
        __syncthreads();                       // prev-iter LDS readers done
        *(uint4*)(Ks + r * 72 + cq)     = kp0;
        *(uint4*)(Ks + r * 72 + cq + 8) = kp1;
        if (i == 0) {
            u16* hb = Rw + (qb0 & 1) * 4608;
            *(uint4*)(hb + r * 72 + cq)     = ri0;
            *(uint4*)(hb + r * 72 + cq + 8) = ri1;
        }
        if (i <= si) {
            u16* hb = Rw + ((qb0 + i + 1) & 1) * 4608;
            *(uint4*)(hb + r * 72 + cq)     = rp0;
            *(uint4*)(hb + r * 72 + cq + 8) = rp1;
        }
        __syncthreads();                       // staged data visible

        // prefetch next tile into regs (overlaps with MFMA below)
        if (i + 1 < 16) {
            const u16* p = Kg + ((size_t)(i + 1) << 16);
            kp0 = *(const uint4*)p; kp1 = *(const uint4*)(p + 8);
        }
        if (i + 1 <= si) {
            const int u = 1024 - s0 + ((i + 1) << 6) + r;
            uint4 z = {0, 0, 0, 0};
            rp0 = z; rp1 = z;
            if (u < 1024) {
                const u16* p = Rg + ((size_t)u << 6);
                rp0 = *(const uint4*)p; rp1 = *(const uint4*)(p + 8);
            }
        }

        // ---- QK^T quadrant: 2mi x 2nj, K=64 ----
        f32x4 aqk[2][2];
#pragma unroll
        for (int mi = 0; mi < 2; mi++)
#pragma unroll
            for (int nj = 0; nj < 2; nj++) aqk[mi][nj] = (f32x4){0.f, 0.f, 0.f, 0.f};
#pragma unroll
        for (int kk = 0; kk < 2; kk++)
#pragma unroll
            for (int nj = 0; nj < 2; nj++) {
                bf16x8 kb = *(const bf16x8*)(Ks + (wt * 32 + nj * 16 + l16) * 72 +
                                             kk * 32 + quad * 8);
#pragma unroll
                for (int mi = 0; mi < 2; mi++)
                    aqk[mi][nj] = __builtin_amdgcn_mfma_f32_16x16x32_bf16(
                        qf[mi][kk], kb, aqk[mi][nj], 0, 0, 0);
            }

        const int eact = (i <= si);
        if (eact) {
            // ---- E^T tiles: rows=u (4 tiles from tau0), cols=s (2 mi) ----
            const int qb = qb0 + i;
            f32x4 ae[4][2];
#pragma unroll
            for (int uj = 0; uj < 4; uj++)
#pragma unroll
                for (int mi = 0; mi < 2; mi++) ae[uj][mi] = (f32x4){0.f, 0.f, 0.f, 0.f};
#pragma unroll
            for (int kk = 0; kk < 2; kk++)
#pragma unroll
                for (int uj = 0; uj < 4; uj++) {
                    const int tau = tau0 + uj;
                    const u16* hp = Rw + ((qb + (tau >> 2)) & 1) * 4608;
                    bf16x8 ra = *(const bf16x8*)(hp + ((tau & 3) * 16 + l16) * 72 +
                                                 kk * 32 + quad * 8);
#pragma unroll
                    for (int mi = 0; mi < 2; mi++)
                        ae[uj][mi] = __builtin_amdgcn_mfma_f32_16x16x32_bf16(
                            ra, qf[mi][kk], ae[uj][mi], 0, 0, 0);
                }
            // pack 4 consecutive-u values -> b64 into row-major Eb[s][c]
#pragma unroll
            for (int uj = 0; uj < 4; uj++)
#pragma unroll
                for (int mi = 0; mi < 2; mi++) {
                    const int scol = ws * 32 + mi * 16 + l16;
                    const int cb = (tau0 + uj) * 16 + quad * 4;
                    uint2 pk;
                    pk.x = (u32)f2bf(ae[uj][mi][0]) | ((u32)f2bf(ae[uj][mi][1]) << 16);
                    pk.y = (u32)f2bf(ae[uj][mi][2]) | ((u32)f2bf(ae[uj][mi][3]) << 16);
                    *(uint2*)(Eb + scol * 132 + cb) = pk;
                }
        }

        // ---- combine + stage to Ssh (wave-local quadrant) ----
#pragma unroll
        for (int mi = 0; mi < 2; mi++)
#pragma unroll
            for (int nj = 0; nj < 2; nj++)
#pragma unroll
                for (int rr = 0; rr < 4; rr++) {
                    const int sl = ws * 32 + mi * 16 + quad * 4 + rr;
                    const int tl = wt * 32 + nj * 16 + l16;
                    float e = 0.f;
                    if (eact) e = bf2f(Eb[sl * 131 + 63 + tl]);  // = [sl][63+tl-sl]
                    Ssh[sl * 72 + tl] = f2bf(aqk[mi][nj][rr] * 0.125f + e);
                }

        // ---- coalesced write of the wave's own 32x32 quadrant ----
        {
            const int row = ws * 32 + (lane >> 1);
            const int col = wt * 32 + ((lane & 1) << 4);
            uint4 v0 = *(const uint4*)(Ssh + row * 72 + col);
            uint4 v1 = *(const uint4*)(Ssh + row * 72 + col + 8);
            u16* op = scores + (((size_t)bh * 1024 + s0 + row) << 10) + t0 + col;
            *(uint4*)op = v0;
            *(uint4*)(op + 8) = v1;
        }
    }
}

// ------------- fused batch-softmax + PV, split over t-halves ---------------
// Opart[th][bh][s][d] = sum_{t in half} softmax_b(scraw)[bh][s][t]*YvT[bh][d][t]
// grid (256, 2) = (16h x 16 s-tiles) x (t-half). Softmax ONCE per fragment
// (partitioned over t). 2 blocks/CU = 8 waves/CU.
__global__ __launch_bounds__(256) void pv_smx(
    const u16* __restrict__ scraw, const u16* __restrict__ YvT,
    float* __restrict__ O0, float* __restrict__ O1)
{
    __shared__ __align__(16) u16 Vt[18432];    // V[4][64][72] = 36 KB
    const int tid = threadIdx.x;
    const int w = tid >> 6, lane = tid & 63;
    const int quad = lane >> 4, l16 = lane & 15;
    const int th = blockIdx.y;                 // t-half
    const int tbase = th << 9;                 // 0 or 512

    // h-major XCD swizzle: XCD k gets h in {2k,2k+1} -> V panels L2-resident
    const int bid = blockIdx.x;
    const int swz = (bid & 7) * 32 + (bid >> 3);
    const int h = swz >> 4, si = swz & 15;
    const int s0 = si << 6;

    // per-lane direct P fragment base (includes t-half offset)
    const u16* Pl = scraw + ((size_t)(h * 1024 + s0 + w * 16 + l16) << 10) +
                    tbase + quad * 8;
    // V staging map
    const int sr0 = tid >> 3, sc0 = (tid & 7) << 3;
    const u16* Vg = YvT + ((size_t)h << 16) + ((size_t)sr0 << 10) + tbase + sc0;

    f32x4 acc[4][4];
#pragma unroll
    for (int b = 0; b < 4; b++)
#pragma unroll
        for (int j = 0; j < 4; j++) acc[b][j] = (f32x4){0.f, 0.f, 0.f, 0.f};

    u32x4 pc[4][2], pn[4][2], vc[4][2], vn[4][2];
#pragma unroll
    for (int b = 0; b < 4; b++) {
        pc[b][0] = *(const u32x4*)(Pl + ((size_t)b << 24));
        pc[b][1] = *(const u32x4*)(Pl + ((size_t)b << 24) + 32);
        vc[b][0] = *(const u32x4*)(Vg + ((size_t)b << 20));
        vc[b][1] = *(const u32x4*)(Vg + ((size_t)b << 20) + (32 << 10));
    }

    for (int t0 = 0; t0 < 512; t0 += 64) {
        __syncthreads();
#pragma unroll
        for (int b = 0; b < 4; b++) {
            *(u32x4*)(Vt + b * 4608 + sr0 * 72 + sc0)        = vc[b][0];
            *(u32x4*)(Vt + b * 4608 + (sr0 + 32) * 72 + sc0) = vc[b][1];
        }
        __syncthreads();

        const int more = (t0 + 64 < 512);
        if (more) {                            // prefetch next chunk (regs)
#pragma unroll
            for (int b = 0; b < 4; b++) {
                pn[b][0] = *(const u32x4*)(Pl + ((size_t)b << 24) + t0 + 64);
                pn[b][1] = *(const u32x4*)(Pl + ((size_t)b << 24) + t0 + 96);
                vn[b][0] = *(const u32x4*)(Vg + ((size_t)b << 20) + t0 + 64);
                vn[b][1] = *(const u32x4*)(Vg + ((size_t)b << 20) + (32 << 10) + t0 + 64);
            }
        }

#pragma unroll
        for (int kk = 0; kk < 2; kk++) {
            // in-register 4-way batch softmax on the raw fragment words
            u32x4 aw[4];
#pragma unroll
            for (int j = 0; j < 4; j++) {
                float x0[4], x1[4];
#pragma unroll
                for (int b = 0; b < 4; b++) {
                    const u32 wd = pc[b][kk][j];
                    x0[b] = __uint_as_float(wd << 16);
                    x1[b] = __uint_as_float(wd & 0xffff0000u);
                }
                const float m0 = fmaxf(fmaxf(x0[0], x0[1]), fmaxf(x0[2], x0[3]));
                const float m1 = fmaxf(fmaxf(x1[0], x1[1]), fmaxf(x1[2], x1[3]));
                float s0v = 0.f, s1v = 0.f;
#pragma unroll
                for (int b = 0; b < 4; b++) {
                    x0[b] = __expf(x0[b] - m0); s0v += x0[b];
                    x1[b] = __expf(x1[b] - m1); s1v += x1[b];
                }
                const float r0 = 1.f / s0v, r1 = 1.f / s1v;
#pragma unroll
                for (int b = 0; b < 4; b++)
                    aw[b][j] = (u32)f2bf(x0[b] * r0) | ((u32)f2bf(x1[b] * r1) << 16);
            }
#pragma unroll
            for (int b = 0; b < 4; b++) {
                const bf16x8 af = __builtin_bit_cast(bf16x8, aw[b]);
#pragma unroll
                for (int nj = 0; nj < 4; nj++) {
                    bf16x8 bv = *(const bf16x8*)(Vt + b * 4608 + (nj * 16 + l16) * 72 +
                                                 kk * 32 + quad * 8);
                    acc[b][nj] = __builtin_amdgcn_mfma_f32_16x16x32_bf16(
                        af, bv, acc[b][nj], 0, 0, 0);
                }
            }
        }

        if (more) {
#pragma unroll
            for (int b = 0; b < 4; b++) {
                pc[b][0] = pn[b][0]; pc[b][1] = pn[b][1];
                vc[b][0] = vn[b][0]; vc[b][1] = vn[b][1];
            }
        }
    }

    float* Op = th ? O1 : O0;
#pragma unroll
    for (int b = 0; b < 4; b++)
#pragma unroll
        for (int nj = 0; nj < 4; nj++)
#pragma unroll
            for (int rr = 0; rr < 4; rr++) {
                const int row = s0 + w * 16 + quad * 4 + rr;
                Op[((((size_t)(b * 16 + h) << 10) + row) << 6) + nj * 16 + l16] =
                    acc[b][nj][rr];
            }
}

// ------------- out = LN(A + Bf [+ Bf2]) * g + beta -------------------------
template<int DTA, int OUT_F32, int TWOB>
__global__ __launch_bounds__(256) void add_ln(
    const void* __restrict__ A, const float* __restrict__ Bf,
    const float* __restrict__ Bf2,
    const float* __restrict__ g, const float* __restrict__ beta,
    void* __restrict__ out)
{
    const int row = blockIdx.x;
    const int tid = threadIdx.x;
    const size_t base = (size_t)row * 1024;
    float v[4], s1 = 0.f, s2 = 0.f;
#pragma unroll
    for (int k = 0; k < 4; k++) {
        const int c = k * 256 + tid;
        float t = load1<DTA>(A, base + c) + Bf[base + c];
        if (TWOB) t += Bf2[base + c];
        v[k] = t; s1 += t; s2 += t * t;
    }
#pragma unroll
    for (int m = 1; m < 64; m <<= 1) {
        s1 += __shfl_xor(s1, m, 64);
        s2 += __shfl_xor(s2, m, 64);
    }
    __shared__ float red[8];
    if ((tid & 63) == 0) { red[(tid >> 6) * 2] = s1; red[(tid >> 6) * 2 + 1] = s2; }
    __syncthreads();
    s1 = red[0] + red[2] + red[4] + red[6];
    s2 = red[1] + red[3] + red[5] + red[7];
    const float mean = s1 * (1.f / 1024.f);
    const float var = s2 * (1.f / 1024.f) - mean * mean;
    const float rstd = rsqrtf(var + 1e-5f);
#pragma unroll
    for (int k = 0; k < 4; k++) {
        const int c = k * 256 + tid;
        float o = (v[k] - mean) * rstd * g[c] + beta[c];
        if (OUT_F32) ((float*)out)[base + c] = o;
        else ((u16*)out)[base + c] = f2bf(o);
    }
}

// ---------------------------------------------------------------------------
extern "C" void kernel_launch(void* const* d_in, const int* in_sizes, int n_in,
                              void* d_out, int out_size, void* d_ws, size_t ws_size,
                              hipStream_t stream)
{
    const float* x    = (const float*)d_in[0];
    const float* wq   = (const float*)d_in[1];
    const float* wk   = (const float*)d_in[2];
    const float* wv   = (const float*)d_in[3];
    const float* relw = (const float*)d_in[4];
    const float* g1   = (const float*)d_in[5];
    const float* be1  = (const float*)d_in[6];
    const float* g2   = (const float*)d_in[7];
    const float* be2  = (const float*)d_in[8];
    const float* w1   = (const float*)d_in[9];
    const float* b1   = (const float*)d_in[10];
    const float* w2   = (const float*)d_in[11];
    const float* b2   = (const float*)d_in[12];

    const size_t NEEDED = ((size_t)224 << 20);
    if (ws_size < NEEDED) {
        sentinel_ws<<<dim3(1024), dim3(256), 0, stream>>>((float*)d_out, (u32)out_size);
        return;
    }

    char* ws = (char*)d_ws;
    float* O0    = (float*)(ws);
    u16*   relwT = (u16*)(ws);                                  // dies before pv
    u16*   Yq    = (u16*)(ws + ((size_t)16 << 20));             // Yq/Yk/Yv contig
    u16*   Yk    = (u16*)(ws + ((size_t)24 << 20));
    u16*   Yv    = (u16*)(ws + ((size_t)32 << 20));
    u16*   h1    = (u16*)(ws + ((size_t)40 << 20));
    u16*   ffn1  = (u16*)(ws + ((size_t)48 << 20));
    float* O1    = (float*)(ws + ((size_t)48 << 20));           // dies at add_ln
    float* ffn2a = (float*)(ws + ((size_t)80 << 20));
    u16*   YvT   = (u16*)(ws + ((size_t)80 << 20));             // dies before ffn2
    u16*   sc    = (u16*)(ws + ((size_t)96 << 20));
    u16*   xb    = (u16*)(ws + ((size_t)96 << 20));             // pre-qk
    u16*   wqb   = (u16*)(ws + ((size_t)104 << 20));            // wq|wk|wv contig
    u16*   wkb   = (u16*)(ws + ((size_t)106 << 20));
    u16*   wvb   = (u16*)(ws + ((size_t)108 << 20));
    u16*   w1b   = (u16*)(ws + ((size_t)96 << 20));             // post-pv
    u16*   w2b   = (u16*)(ws + ((size_t)104 << 20));
    float* ffn2b = (float*)(ws + ((size_t)112 << 20));          // post-pv

    dim3 blk(256);
    const u32 M4 = 4u << 20, M1 = 1u << 20;

    // fp32 -> bf16 staging + relw transpose
    cvt_f32_bf16<<<dim3(M4 / 1024), blk, 0, stream>>>(x,  xb,  M4);
    cvt_f32_bf16<<<dim3(M1 / 1024), blk, 0, stream>>>(wq, wqb, M1);
    cvt_f32_bf16<<<dim3(M1 / 1024), blk, 0, stream>>>(wk, wkb, M1);
    cvt_f32_bf16<<<dim3(M1 / 1024), blk, 0, stream>>>(wv, wvb, M1);
    relw_tr<<<dim3(16, 64), blk, 0, stream>>>(relw, relwT);

    // fused QKV projection: B=[wq;wk;wv] (3072x1024), C split into Yq/Yk/Yv
    // 768 blocks = 3/CU -> BK=64 GL16 schedule (STAGE=1)
    mfma_gemm<0,0,0,1,1,0><<<dim3(24, 32), blk, 0, stream>>>(
        xb, wqb, nullptr, Yq, nullptr, 4096, 3072, 1024, 1024);
    yv_tr<<<dim3(16, 64), blk, 0, stream>>>(Yv, YvT);

    // scores strip kernel (raw) + fused batch-softmax+PV (t-half split)
    qk_strip<<<dim3(16, 64), blk, 0, stream>>>(Yq, Yk, relwT, sc);
    pv_smx<<<dim3(256, 2), blk, 0, stream>>>(sc, YvT, O0, O1);

    // h1 = LN(x + O0 + O1)
    add_ln<1,0,1><<<dim3(4096), blk, 0, stream>>>(x, O0, O1, g1, be1, h1);

    // FFN weights -> bf16 (scores region dead after pv)
    cvt_f32_bf16<<<dim3(M4 / 1024), blk, 0, stream>>>(w1, w1b, M4);
    cvt_f32_bf16<<<dim3(M4 / 1024), blk, 0, stream>>>(w2, w2b, M4);

    // FFN: ffn1 1024 blocks = 4/CU -> STAGE=1 BK=64.
    mfma_gemm<1,0,1,0,1,0><<<dim3(32, 32), blk, 0, stream>>>(
        h1, w1b, b1, ffn1, nullptr, 4096, 4096, 1024, 1024);
    // ffn2: K-split x2 (z-dim) -> 512 blocks = 2/CU; partials ffn2a/ffn2b.
    mfma_gemm<0,1,1,0,0,1><<<dim3(8, 32, 2), blk, 0, stream>>>(
        ffn1, w2b, b2, ffn2a, ffn2b, 4096, 1024, 2048, 4096);

    // out = LN(h1 + ffn2a + ffn2b) -> f32
    add_ln<0,1,1><<<dim3(4096), blk, 0, stream>>>(h1, ffn2a, ffn2b, g2, be2, (float*)d_out);
}